// Round 2
// baseline (3590.744 us; speedup 1.0000x reference)
//
#include <hip/hip_runtime.h>
#include <hip/hip_bf16.h>
#include <math.h>

#define T_TOK 8192
#define H_DIM 1024
#define E_EXP 8
#define K_TOP 2
#define I_DIM 2048

#define TM 64
#define TN 64
#define BK 16
#define LDSP 65   // padded LDS row stride (fp32) to break bank conflicts

// ---------------------------------------------------------------------------
// Workspace layout (bytes):
//   0    : cnt[8]      int
//   32   : cursor[8]   int
//   64   : probsum[8]  float
//   96   : offs[8]     int
//   256  : tok_e[T*2]  int
//   +64K : tok_w[T*2]  float
//   +64K : idx_list[T*K] int
//   +64K : wgt_list[T*K] float
//   262400: hdn — compact: [T*K][I] float (134 MB); seq fallback: [T][I]
// ---------------------------------------------------------------------------

__global__ __launch_bounds__(256) void gate_kernel(
    const float* __restrict__ xt, const float* __restrict__ gw,
    int* __restrict__ cnt, float* __restrict__ probsum,
    int* __restrict__ tok_e, float* __restrict__ tok_w)
{
    __shared__ float s_probs[4][8];
    __shared__ int   s_cnt[8];
    int tid = threadIdx.x;
    if (tid < 8) s_cnt[tid] = 0;
    __syncthreads();

    int wave = tid >> 6, lane = tid & 63;
    int t = blockIdx.x * 4 + wave;

    float acc[8];
#pragma unroll
    for (int e = 0; e < 8; e++) acc[e] = 0.f;
    const float* xrow = xt + (size_t)t * H_DIM;
    for (int k = lane; k < H_DIM; k += 64) {
        float xv = xrow[k];
#pragma unroll
        for (int e = 0; e < 8; e++) acc[e] = fmaf(xv, gw[e * H_DIM + k], acc[e]);
    }
#pragma unroll
    for (int off = 32; off > 0; off >>= 1) {
#pragma unroll
        for (int e = 0; e < 8; e++) acc[e] += __shfl_down(acc[e], off);
    }
    if (lane == 0) {
        float mx = acc[0];
#pragma unroll
        for (int e = 1; e < 8; e++) mx = fmaxf(mx, acc[e]);
        float p[8]; float sum = 0.f;
#pragma unroll
        for (int e = 0; e < 8; e++) { p[e] = expf(acc[e] - mx); sum += p[e]; }
        float inv = 1.f / sum;
#pragma unroll
        for (int e = 0; e < 8; e++) p[e] *= inv;
        // top-2, index-stable ties (matches jax.lax.top_k)
        int i0 = 0;
#pragma unroll
        for (int e = 1; e < 8; e++) if (p[e] > p[i0]) i0 = e;
        int i1 = (i0 == 0) ? 1 : 0;
#pragma unroll
        for (int e = 0; e < 8; e++) if (e != i0 && p[e] > p[i1]) i1 = e;
        float w0 = p[i0], w1v = p[i1];
        float denom = w0 + w1v + 1e-6f;
        tok_e[t * 2 + 0] = i0;            tok_e[t * 2 + 1] = i1;
        tok_w[t * 2 + 0] = w0 / denom;    tok_w[t * 2 + 1] = w1v / denom;
        atomicAdd(&s_cnt[i0], 1);
        atomicAdd(&s_cnt[i1], 1);
#pragma unroll
        for (int e = 0; e < 8; e++) s_probs[wave][e] = p[e];
    }
    __syncthreads();
    if (tid < 8) {
        float s = s_probs[0][tid] + s_probs[1][tid] + s_probs[2][tid] + s_probs[3][tid];
        atomicAdd(&probsum[tid], s);
        if (s_cnt[tid]) atomicAdd(&cnt[tid], s_cnt[tid]);
    }
}

__global__ void offs_aux_kernel(const int* __restrict__ cnt,
                                const float* __restrict__ probsum,
                                int* __restrict__ offs, int* __restrict__ cursor,
                                float* __restrict__ out_aux)
{
    if (threadIdx.x == 0 && blockIdx.x == 0) {
        int o = 0; float aux = 0.f;
        for (int e = 0; e < E_EXP; e++) {
            offs[e] = o; cursor[e] = o; o += cnt[e];
            aux += (float)cnt[e] * probsum[e];
        }
        out_aux[0] = aux * (float)E_EXP / ((float)T_TOK * (float)T_TOK);
    }
}

__global__ __launch_bounds__(256) void scatter_kernel(
    const int* __restrict__ tok_e, const float* __restrict__ tok_w,
    int* __restrict__ cursor, int* __restrict__ idx_list, float* __restrict__ wgt_list)
{
    int t = blockIdx.x * 256 + threadIdx.x;
#pragma unroll
    for (int s = 0; s < K_TOP; s++) {
        int e = tok_e[t * 2 + s];
        int pos = atomicAdd(&cursor[e], 1);
        idx_list[pos] = t;
        wgt_list[pos] = tok_w[t * 2 + s];
    }
}

// GEMM1: hdn[pos, i] = silu(x[tok]·w1[e,i,:]) * (x[tok]·w3[e,i,:])
__global__ __launch_bounds__(256) void gemm1_kernel(
    const float* __restrict__ xt, const float* __restrict__ w1,
    const float* __restrict__ w3,
    const int* __restrict__ cnt, const int* __restrict__ offs,
    const int* __restrict__ idx_list,
    float* __restrict__ hdn, int e_param, int compact)
{
    int e = (e_param >= 0) ? e_param : (int)blockIdx.z;
    int n_e = cnt[e];
    int row0 = blockIdx.y * TM;
    if (row0 >= n_e) return;
    int col0 = blockIdx.x * TN;
    int lbase = offs[e];
    size_t hbase = compact ? (size_t)lbase : 0;

    __shared__ float As[BK * LDSP];
    __shared__ float B1s[BK * LDSP];
    __shared__ float B3s[BK * LDSP];
    __shared__ int toks[TM];

    int tid = threadIdx.x;
    if (tid < TM) {
        int r = row0 + tid;
        toks[tid] = (r < n_e) ? idx_list[lbase + r] : -1;
    }
    __syncthreads();

    const float* w1e = w1 + (size_t)e * I_DIM * H_DIM;
    const float* w3e = w3 + (size_t)e * I_DIM * H_DIM;

    float accu[4][4], accv[4][4];
#pragma unroll
    for (int i = 0; i < 4; i++)
#pragma unroll
        for (int j = 0; j < 4; j++) { accu[i][j] = 0.f; accv[i][j] = 0.f; }

    int tx = tid & 15, ty = tid >> 4;
    // staging: 256 threads × one float4 each per buffer = 64 rows × 16 k
    int sm = tid >> 2;            // row 0..63
    int sk = (tid & 3) * 4;       // k offset 0,4,8,12

    for (int k0 = 0; k0 < H_DIM; k0 += BK) {
        int tok = toks[sm];
        float4 av = (tok >= 0)
            ? *(const float4*)&xt[(size_t)tok * H_DIM + k0 + sk]
            : make_float4(0.f, 0.f, 0.f, 0.f);
        float4 b1v = *(const float4*)&w1e[(size_t)(col0 + sm) * H_DIM + k0 + sk];
        float4 b3v = *(const float4*)&w3e[(size_t)(col0 + sm) * H_DIM + k0 + sk];
        As[(sk + 0) * LDSP + sm] = av.x;  As[(sk + 1) * LDSP + sm] = av.y;
        As[(sk + 2) * LDSP + sm] = av.z;  As[(sk + 3) * LDSP + sm] = av.w;
        B1s[(sk + 0) * LDSP + sm] = b1v.x; B1s[(sk + 1) * LDSP + sm] = b1v.y;
        B1s[(sk + 2) * LDSP + sm] = b1v.z; B1s[(sk + 3) * LDSP + sm] = b1v.w;
        B3s[(sk + 0) * LDSP + sm] = b3v.x; B3s[(sk + 1) * LDSP + sm] = b3v.y;
        B3s[(sk + 2) * LDSP + sm] = b3v.z; B3s[(sk + 3) * LDSP + sm] = b3v.w;
        __syncthreads();
#pragma unroll
        for (int k = 0; k < BK; k++) {
            float a[4], b1[4], b3[4];
#pragma unroll
            for (int i = 0; i < 4; i++) a[i] = As[k * LDSP + ty + 16 * i];
#pragma unroll
            for (int j = 0; j < 4; j++) {
                b1[j] = B1s[k * LDSP + tx + 16 * j];
                b3[j] = B3s[k * LDSP + tx + 16 * j];
            }
#pragma unroll
            for (int i = 0; i < 4; i++)
#pragma unroll
                for (int j = 0; j < 4; j++) {
                    accu[i][j] = fmaf(a[i], b1[j], accu[i][j]);
                    accv[i][j] = fmaf(a[i], b3[j], accv[i][j]);
                }
        }
        __syncthreads();
    }

#pragma unroll
    for (int i = 0; i < 4; i++) {
        int r = ty + 16 * i;
        if (row0 + r < n_e) {
            float* hrow = hdn + (hbase + row0 + r) * (size_t)I_DIM + col0;
#pragma unroll
            for (int j = 0; j < 4; j++) {
                float u = accu[i][j], v = accv[i][j];
                float s = u / (1.f + expf(-u));   // silu
                hrow[tx + 16 * j] = s * v;
            }
        }
    }
}

// GEMM2: out[tok, h] += wgt * (hdn[pos,:]·w2[e,h,:])
__global__ __launch_bounds__(256) void gemm2_kernel(
    const float* __restrict__ hdn, const float* __restrict__ w2,
    const int* __restrict__ cnt, const int* __restrict__ offs,
    const int* __restrict__ idx_list, const float* __restrict__ wgt_list,
    float* __restrict__ out, int e_param, int compact)
{
    int e = (e_param >= 0) ? e_param : (int)blockIdx.z;
    int n_e = cnt[e];
    int row0 = blockIdx.y * TM;
    if (row0 >= n_e) return;
    int col0 = blockIdx.x * TN;    // over H
    int lbase = offs[e];
    size_t hbase = compact ? (size_t)lbase : 0;

    __shared__ float As[BK * LDSP];
    __shared__ float Bs[BK * LDSP];

    int tid = threadIdx.x;
    const float* w2e = w2 + (size_t)e * H_DIM * I_DIM;

    float acc[4][4];
#pragma unroll
    for (int i = 0; i < 4; i++)
#pragma unroll
        for (int j = 0; j < 4; j++) acc[i][j] = 0.f;

    int tx = tid & 15, ty = tid >> 4;
    int sm = tid >> 2;
    int sk = (tid & 3) * 4;

    for (int k0 = 0; k0 < I_DIM; k0 += BK) {
        float4 av = (row0 + sm < n_e)
            ? *(const float4*)&hdn[(hbase + row0 + sm) * (size_t)I_DIM + k0 + sk]
            : make_float4(0.f, 0.f, 0.f, 0.f);
        float4 bv = *(const float4*)&w2e[(size_t)(col0 + sm) * I_DIM + k0 + sk];
        As[(sk + 0) * LDSP + sm] = av.x;  As[(sk + 1) * LDSP + sm] = av.y;
        As[(sk + 2) * LDSP + sm] = av.z;  As[(sk + 3) * LDSP + sm] = av.w;
        Bs[(sk + 0) * LDSP + sm] = bv.x;  Bs[(sk + 1) * LDSP + sm] = bv.y;
        Bs[(sk + 2) * LDSP + sm] = bv.z;  Bs[(sk + 3) * LDSP + sm] = bv.w;
        __syncthreads();
#pragma unroll
        for (int k = 0; k < BK; k++) {
            float a[4], b[4];
#pragma unroll
            for (int i = 0; i < 4; i++) a[i] = As[k * LDSP + ty + 16 * i];
#pragma unroll
            for (int j = 0; j < 4; j++) b[j] = Bs[k * LDSP + tx + 16 * j];
#pragma unroll
            for (int i = 0; i < 4; i++)
#pragma unroll
                for (int j = 0; j < 4; j++) acc[i][j] = fmaf(a[i], b[j], acc[i][j]);
        }
        __syncthreads();
    }

#pragma unroll
    for (int i = 0; i < 4; i++) {
        int r = ty + 16 * i;
        if (row0 + r < n_e) {
            int t = idx_list[lbase + row0 + r];
            float wt = wgt_list[lbase + row0 + r];
            float* orow = out + (size_t)t * H_DIM + col0;
#pragma unroll
            for (int j = 0; j < 4; j++)
                atomicAdd(&orow[tx + 16 * j], wt * acc[i][j]);
        }
    }
}

extern "C" void kernel_launch(void* const* d_in, const int* in_sizes, int n_in,
                              void* d_out, int out_size, void* d_ws, size_t ws_size,
                              hipStream_t stream) {
    const float* x  = (const float*)d_in[0];
    const float* gw = (const float*)d_in[1];
    const float* w1 = (const float*)d_in[2];
    const float* w2 = (const float*)d_in[3];
    const float* w3 = (const float*)d_in[4];
    float* out = (float*)d_out;

    char* ws = (char*)d_ws;
    int*   cnt      = (int*)(ws + 0);
    int*   cursor   = (int*)(ws + 32);
    float* probsum  = (float*)(ws + 64);
    int*   offs     = (int*)(ws + 96);
    int*   tok_e    = (int*)(ws + 256);
    float* tok_w    = (float*)(ws + 256 + 65536);
    int*   idx_list = (int*)(ws + 256 + 2 * 65536);
    float* wgt_list = (float*)(ws + 256 + 3 * 65536);
    size_t hdn_off  = 256 + 4 * 65536;   // 262400, 256-aligned
    float* hdn      = (float*)(ws + hdn_off);

    size_t need_compact = hdn_off + (size_t)T_TOK * K_TOP * I_DIM * sizeof(float);
    int compact = (ws_size >= need_compact) ? 1 : 0;

    hipMemsetAsync(ws, 0, 128, stream);                               // cnt/cursor/probsum
    hipMemsetAsync(d_out, 0, (size_t)T_TOK * H_DIM * sizeof(float), stream);

    gate_kernel<<<T_TOK / 4, 256, 0, stream>>>(x, gw, cnt, probsum, tok_e, tok_w);
    offs_aux_kernel<<<1, 64, 0, stream>>>(cnt, probsum, offs, cursor,
                                          out + (size_t)T_TOK * H_DIM);
    scatter_kernel<<<T_TOK / 256, 256, 0, stream>>>(tok_e, tok_w, cursor,
                                                    idx_list, wgt_list);
    if (compact) {
        dim3 g1(I_DIM / TN, T_TOK / TM, E_EXP);
        gemm1_kernel<<<g1, 256, 0, stream>>>(x, w1, w3, cnt, offs, idx_list, hdn, -1, 1);
        dim3 g2(H_DIM / TN, T_TOK / TM, E_EXP);
        gemm2_kernel<<<g2, 256, 0, stream>>>(hdn, w2, cnt, offs, idx_list, wgt_list,
                                             out, -1, 1);
    } else {
        // sequential per-expert fallback reusing a T*I hdn buffer
        for (int e = 0; e < E_EXP; e++) {
            gemm1_kernel<<<dim3(I_DIM / TN, T_TOK / TM, 1), 256, 0, stream>>>(
                x, w1, w3, cnt, offs, idx_list, hdn, e, 0);
            gemm2_kernel<<<dim3(H_DIM / TN, T_TOK / TM, 1), 256, 0, stream>>>(
                hdn, w2, cnt, offs, idx_list, wgt_list, out, e, 0);
        }
    }
}

// Round 3
// 1759.313 us; speedup vs baseline: 2.0410x; 2.0410x over previous
//
#include <hip/hip_runtime.h>
#include <hip/hip_bf16.h>
#include <math.h>

#define T_TOK 8192
#define H_DIM 1024
#define E_EXP 8
#define K_TOP 2
#define I_DIM 2048

typedef short bf16x8 __attribute__((ext_vector_type(8)));
typedef float f32x4 __attribute__((ext_vector_type(4)));

#define MFMA16(a, b, c) __builtin_amdgcn_mfma_f32_16x16x32_bf16((a), (b), (c), 0, 0, 0)

// LDS swizzle (units = shorts, row stride 32 shorts = 64B):
// XOR 16B-slot index with (row&7) -> conflict-free ds_read_b128 fragment reads.
#define SWZ(r, k) ((((r) * 32) + (k)) ^ (((r) & 7) << 3))

__device__ __forceinline__ unsigned short f2bf(float f) {
    unsigned u = __builtin_bit_cast(unsigned, f);
    u += 0x7fffu + ((u >> 16) & 1u);          // RNE
    return (unsigned short)(u >> 16);
}
__device__ __forceinline__ float bf2f(unsigned short s) {
    return __builtin_bit_cast(float, ((unsigned)s) << 16);
}
// split fp32x4 -> bf16 hi plane + bf16 lo (residual) plane, packed 2x per dword
__device__ __forceinline__ void split4(float4 v, unsigned* hi, unsigned* lo) {
    unsigned short hx = f2bf(v.x), hy = f2bf(v.y), hz = f2bf(v.z), hw = f2bf(v.w);
    unsigned short lx = f2bf(v.x - bf2f(hx)), ly = f2bf(v.y - bf2f(hy));
    unsigned short lz = f2bf(v.z - bf2f(hz)), lw = f2bf(v.w - bf2f(hw));
    hi[0] = (unsigned)hx | ((unsigned)hy << 16);
    hi[1] = (unsigned)hz | ((unsigned)hw << 16);
    lo[0] = (unsigned)lx | ((unsigned)ly << 16);
    lo[1] = (unsigned)lz | ((unsigned)lw << 16);
}

// ---------------------------------------------------------------------------
// Workspace layout (bytes):
//   0    : cnt[8] | 32: cursor[8] | 64: probsum[8] | 96: offs[8]
//   256  : tok_e[T*2] int | +64K: tok_w[T*2] f32
//   +64K : idx_list[T*K] int | +64K: wgt_list[T*K] f32
//   262400: hdn fp32 — compact: [T*K][I] (134 MB); fallback: [T][I]
// ---------------------------------------------------------------------------

__global__ __launch_bounds__(256) void gate_kernel(
    const float* __restrict__ xt, const float* __restrict__ gw,
    int* __restrict__ cnt, float* __restrict__ probsum,
    int* __restrict__ tok_e, float* __restrict__ tok_w)
{
    __shared__ float s_probs[4][8];
    __shared__ int   s_cnt[8];
    int tid = threadIdx.x;
    if (tid < 8) s_cnt[tid] = 0;
    __syncthreads();

    int wave = tid >> 6, lane = tid & 63;
    int t = blockIdx.x * 4 + wave;

    float acc[8];
#pragma unroll
    for (int e = 0; e < 8; e++) acc[e] = 0.f;
    const float* xrow = xt + (size_t)t * H_DIM;
    for (int k = lane; k < H_DIM; k += 64) {
        float xv = xrow[k];
#pragma unroll
        for (int e = 0; e < 8; e++) acc[e] = fmaf(xv, gw[e * H_DIM + k], acc[e]);
    }
#pragma unroll
    for (int off = 32; off > 0; off >>= 1) {
#pragma unroll
        for (int e = 0; e < 8; e++) acc[e] += __shfl_down(acc[e], off);
    }
    if (lane == 0) {
        float mx = acc[0];
#pragma unroll
        for (int e = 1; e < 8; e++) mx = fmaxf(mx, acc[e]);
        float p[8]; float sum = 0.f;
#pragma unroll
        for (int e = 0; e < 8; e++) { p[e] = expf(acc[e] - mx); sum += p[e]; }
        float inv = 1.f / sum;
#pragma unroll
        for (int e = 0; e < 8; e++) p[e] *= inv;
        int i0 = 0;
#pragma unroll
        for (int e = 1; e < 8; e++) if (p[e] > p[i0]) i0 = e;
        int i1 = (i0 == 0) ? 1 : 0;
#pragma unroll
        for (int e = 0; e < 8; e++) if (e != i0 && p[e] > p[i1]) i1 = e;
        float w0 = p[i0], w1v = p[i1];
        float denom = w0 + w1v + 1e-6f;
        tok_e[t * 2 + 0] = i0;            tok_e[t * 2 + 1] = i1;
        tok_w[t * 2 + 0] = w0 / denom;    tok_w[t * 2 + 1] = w1v / denom;
        atomicAdd(&s_cnt[i0], 1);
        atomicAdd(&s_cnt[i1], 1);
#pragma unroll
        for (int e = 0; e < 8; e++) s_probs[wave][e] = p[e];
    }
    __syncthreads();
    if (tid < 8) {
        float s = s_probs[0][tid] + s_probs[1][tid] + s_probs[2][tid] + s_probs[3][tid];
        atomicAdd(&probsum[tid], s);
        if (s_cnt[tid]) atomicAdd(&cnt[tid], s_cnt[tid]);
    }
}

__global__ void offs_aux_kernel(const int* __restrict__ cnt,
                                const float* __restrict__ probsum,
                                int* __restrict__ offs, int* __restrict__ cursor,
                                float* __restrict__ out_aux)
{
    if (threadIdx.x == 0 && blockIdx.x == 0) {
        int o = 0; float aux = 0.f;
        for (int e = 0; e < E_EXP; e++) {
            offs[e] = o; cursor[e] = o; o += cnt[e];
            aux += (float)cnt[e] * probsum[e];
        }
        out_aux[0] = aux * (float)E_EXP / ((float)T_TOK * (float)T_TOK);
    }
}

__global__ __launch_bounds__(256) void scatter_kernel(
    const int* __restrict__ tok_e, const float* __restrict__ tok_w,
    int* __restrict__ cursor, int* __restrict__ idx_list, float* __restrict__ wgt_list)
{
    int t = blockIdx.x * 256 + threadIdx.x;
#pragma unroll
    for (int s = 0; s < K_TOP; s++) {
        int e = tok_e[t * 2 + s];
        int pos = atomicAdd(&cursor[e], 1);
        idx_list[pos] = t;
        wgt_list[pos] = tok_w[t * 2 + s];
    }
}

// ---------------------------------------------------------------------------
// GEMM1 (MFMA split-bf16): hdn[pos,i] = silu(x·w1^T) * (x·w3^T)
// block tile 128(rows) x 64(cols), BK=32; 4 waves 2x2, per-wave 64x32
// ---------------------------------------------------------------------------
__global__ __launch_bounds__(256) void gemm1_mfma(
    const float* __restrict__ xt, const float* __restrict__ w1,
    const float* __restrict__ w3,
    const int* __restrict__ cnt, const int* __restrict__ offs,
    const int* __restrict__ idx_list,
    float* __restrict__ hdn, int e_param, int compact)
{
    int e = (e_param >= 0) ? e_param : (int)blockIdx.z;
    int n_e = cnt[e];
    int row0 = blockIdx.y * 128;
    if (row0 >= n_e) return;
    int col0 = blockIdx.x * 64;
    int lbase = offs[e];
    size_t hbase = compact ? (size_t)lbase : 0;

    __shared__ unsigned short Ah[128 * 32], Al[128 * 32];
    __shared__ unsigned short B1h[64 * 32], B1l[64 * 32];
    __shared__ unsigned short B3h[64 * 32], B3l[64 * 32];
    __shared__ int toks[128];

    int tid = threadIdx.x;
    if (tid < 128) {
        int r = row0 + tid;
        toks[tid] = (r < n_e) ? idx_list[lbase + r] : -1;
    }
    __syncthreads();

    const float* w1e = w1 + (size_t)e * I_DIM * H_DIM;
    const float* w3e = w3 + (size_t)e * I_DIM * H_DIM;

    f32x4 accu[4][2], accv[4][2];
#pragma unroll
    for (int i = 0; i < 4; i++)
#pragma unroll
        for (int j = 0; j < 2; j++) {
            accu[i][j] = (f32x4)(0.f);
            accv[i][j] = (f32x4)(0.f);
        }

    int lane = tid & 63, wid = tid >> 6;
    int wm = wid >> 1, wn = wid & 1;
    int lr = lane & 15, lq = lane >> 4;

    for (int k0 = 0; k0 < H_DIM; k0 += 32) {
        // --- stage A (x gathered): 128x32 fp32 -> hi/lo bf16
#pragma unroll
        for (int p = 0; p < 4; p++) {
            int idx = tid + p * 256;
            int row = idx >> 3, kq = (idx & 7) << 2;
            int tok = toks[row];
            float4 v = (tok >= 0)
                ? *(const float4*)&xt[(size_t)tok * H_DIM + k0 + kq]
                : make_float4(0.f, 0.f, 0.f, 0.f);
            unsigned hi[2], lo[2];
            split4(v, hi, lo);
            int s = SWZ(row, kq);
            *(uint2*)&Ah[s] = make_uint2(hi[0], hi[1]);
            *(uint2*)&Al[s] = make_uint2(lo[0], lo[1]);
        }
        // --- stage B1/B3 (w rows): 64x32 each
#pragma unroll
        for (int p = 0; p < 2; p++) {
            int idx = tid + p * 256;
            int row = idx >> 3, kq = (idx & 7) << 2;
            size_t goff = (size_t)(col0 + row) * H_DIM + k0 + kq;
            float4 v1 = *(const float4*)&w1e[goff];
            float4 v3 = *(const float4*)&w3e[goff];
            unsigned hi[2], lo[2];
            int s = SWZ(row, kq);
            split4(v1, hi, lo);
            *(uint2*)&B1h[s] = make_uint2(hi[0], hi[1]);
            *(uint2*)&B1l[s] = make_uint2(lo[0], lo[1]);
            split4(v3, hi, lo);
            *(uint2*)&B3h[s] = make_uint2(hi[0], hi[1]);
            *(uint2*)&B3l[s] = make_uint2(lo[0], lo[1]);
        }
        __syncthreads();

        bf16x8 ah[4], al[4];
#pragma unroll
        for (int i = 0; i < 4; i++) {
            int r = wm * 64 + i * 16 + lr;
            int s = SWZ(r, lq * 8);
            ah[i] = *(const bf16x8*)&Ah[s];
            al[i] = *(const bf16x8*)&Al[s];
        }
#pragma unroll
        for (int j = 0; j < 2; j++) {
            int rb = wn * 32 + j * 16 + lr;
            int s = SWZ(rb, lq * 8);
            bf16x8 b1h = *(const bf16x8*)&B1h[s];
            bf16x8 b1l = *(const bf16x8*)&B1l[s];
            bf16x8 b3h = *(const bf16x8*)&B3h[s];
            bf16x8 b3l = *(const bf16x8*)&B3l[s];
#pragma unroll
            for (int i = 0; i < 4; i++) {
                accu[i][j] = MFMA16(ah[i], b1h, accu[i][j]);
                accu[i][j] = MFMA16(ah[i], b1l, accu[i][j]);
                accu[i][j] = MFMA16(al[i], b1h, accu[i][j]);
                accv[i][j] = MFMA16(ah[i], b3h, accv[i][j]);
                accv[i][j] = MFMA16(ah[i], b3l, accv[i][j]);
                accv[i][j] = MFMA16(al[i], b3h, accv[i][j]);
            }
        }
        __syncthreads();
    }

#pragma unroll
    for (int i = 0; i < 4; i++) {
#pragma unroll
        for (int r = 0; r < 4; r++) {
            int lrow = wm * 64 + i * 16 + lq * 4 + r;
            int grow = row0 + lrow;
            if (grow < n_e) {
                float* hrow = hdn + (hbase + grow) * (size_t)I_DIM + col0;
#pragma unroll
                for (int j = 0; j < 2; j++) {
                    float u = accu[i][j][r];
                    float v = accv[i][j][r];
                    float si = u / (1.f + expf(-u));
                    hrow[wn * 32 + j * 16 + lr] = si * v;
                }
            }
        }
    }
}

// ---------------------------------------------------------------------------
// GEMM2 (MFMA split-bf16): out[tok,h] += wgt * (hdn · w2^T)
// block tile 128(rows) x 128(cols over H), BK=32; 4 waves 2x2, per-wave 64x64
// ---------------------------------------------------------------------------
__global__ __launch_bounds__(256) void gemm2_mfma(
    const float* __restrict__ hdn, const float* __restrict__ w2,
    const int* __restrict__ cnt, const int* __restrict__ offs,
    const int* __restrict__ idx_list, const float* __restrict__ wgt_list,
    float* __restrict__ out, int e_param, int compact)
{
    int e = (e_param >= 0) ? e_param : (int)blockIdx.z;
    int n_e = cnt[e];
    int row0 = blockIdx.y * 128;
    if (row0 >= n_e) return;
    int col0 = blockIdx.x * 128;
    int lbase = offs[e];
    size_t hbase = compact ? (size_t)lbase : 0;

    __shared__ unsigned short Ah[128 * 32], Al[128 * 32];
    __shared__ unsigned short Bh[128 * 32], Bl[128 * 32];
    __shared__ int   s_tok[128];
    __shared__ float s_wgt[128];

    int tid = threadIdx.x;
    if (tid < 128) {
        int r = row0 + tid;
        s_tok[tid] = (r < n_e) ? idx_list[lbase + r] : -1;
        s_wgt[tid] = (r < n_e) ? wgt_list[lbase + r] : 0.f;
    }

    const float* w2e = w2 + (size_t)e * H_DIM * I_DIM;

    f32x4 acc[4][4];
#pragma unroll
    for (int i = 0; i < 4; i++)
#pragma unroll
        for (int j = 0; j < 4; j++) acc[i][j] = (f32x4)(0.f);

    int lane = tid & 63, wid = tid >> 6;
    int wm = wid >> 1, wn = wid & 1;
    int lr = lane & 15, lq = lane >> 4;

    for (int k0 = 0; k0 < I_DIM; k0 += 32) {
        // --- stage A (hdn) 128x32
#pragma unroll
        for (int p = 0; p < 4; p++) {
            int idx = tid + p * 256;
            int row = idx >> 3, kq = (idx & 7) << 2;
            float4 v = (row0 + row < n_e)
                ? *(const float4*)&hdn[(hbase + row0 + row) * (size_t)I_DIM + k0 + kq]
                : make_float4(0.f, 0.f, 0.f, 0.f);
            unsigned hi[2], lo[2];
            split4(v, hi, lo);
            int s = SWZ(row, kq);
            *(uint2*)&Ah[s] = make_uint2(hi[0], hi[1]);
            *(uint2*)&Al[s] = make_uint2(lo[0], lo[1]);
        }
        // --- stage B (w2) 128x32
#pragma unroll
        for (int p = 0; p < 4; p++) {
            int idx = tid + p * 256;
            int row = idx >> 3, kq = (idx & 7) << 2;
            float4 v = *(const float4*)&w2e[(size_t)(col0 + row) * I_DIM + k0 + kq];
            unsigned hi[2], lo[2];
            split4(v, hi, lo);
            int s = SWZ(row, kq);
            *(uint2*)&Bh[s] = make_uint2(hi[0], hi[1]);
            *(uint2*)&Bl[s] = make_uint2(lo[0], lo[1]);
        }
        __syncthreads();

        bf16x8 ah[4], al[4];
#pragma unroll
        for (int i = 0; i < 4; i++) {
            int r = wm * 64 + i * 16 + lr;
            int s = SWZ(r, lq * 8);
            ah[i] = *(const bf16x8*)&Ah[s];
            al[i] = *(const bf16x8*)&Al[s];
        }
#pragma unroll
        for (int j = 0; j < 4; j++) {
            int rb = wn * 64 + j * 16 + lr;
            int s = SWZ(rb, lq * 8);
            bf16x8 bh = *(const bf16x8*)&Bh[s];
            bf16x8 bl = *(const bf16x8*)&Bl[s];
#pragma unroll
            for (int i = 0; i < 4; i++) {
                acc[i][j] = MFMA16(ah[i], bh, acc[i][j]);
                acc[i][j] = MFMA16(ah[i], bl, acc[i][j]);
                acc[i][j] = MFMA16(al[i], bh, acc[i][j]);
            }
        }
        __syncthreads();
    }

#pragma unroll
    for (int i = 0; i < 4; i++) {
#pragma unroll
        for (int r = 0; r < 4; r++) {
            int lrow = wm * 64 + i * 16 + lq * 4 + r;
            int grow = row0 + lrow;
            if (grow < n_e) {
                int t = s_tok[lrow];
                float wt = s_wgt[lrow];
                float* orow = out + (size_t)t * H_DIM + col0;
#pragma unroll
                for (int j = 0; j < 4; j++)
                    atomicAdd(&orow[wn * 64 + j * 16 + lr], wt * acc[i][j][r]);
            }
        }
    }
}

extern "C" void kernel_launch(void* const* d_in, const int* in_sizes, int n_in,
                              void* d_out, int out_size, void* d_ws, size_t ws_size,
                              hipStream_t stream) {
    const float* x  = (const float*)d_in[0];
    const float* gw = (const float*)d_in[1];
    const float* w1 = (const float*)d_in[2];
    const float* w2 = (const float*)d_in[3];
    const float* w3 = (const float*)d_in[4];
    float* out = (float*)d_out;

    char* ws = (char*)d_ws;
    int*   cnt      = (int*)(ws + 0);
    int*   cursor   = (int*)(ws + 32);
    float* probsum  = (float*)(ws + 64);
    int*   offs     = (int*)(ws + 96);
    int*   tok_e    = (int*)(ws + 256);
    float* tok_w    = (float*)(ws + 256 + 65536);
    int*   idx_list = (int*)(ws + 256 + 2 * 65536);
    float* wgt_list = (float*)(ws + 256 + 3 * 65536);
    size_t hdn_off  = 256 + 4 * 65536;   // 262400, 256-aligned
    float* hdn      = (float*)(ws + hdn_off);

    size_t need_compact = hdn_off + (size_t)T_TOK * K_TOP * I_DIM * sizeof(float);
    int compact = (ws_size >= need_compact) ? 1 : 0;

    hipMemsetAsync(ws, 0, 128, stream);
    hipMemsetAsync(d_out, 0, (size_t)T_TOK * H_DIM * sizeof(float), stream);

    gate_kernel<<<T_TOK / 4, 256, 0, stream>>>(x, gw, cnt, probsum, tok_e, tok_w);
    offs_aux_kernel<<<1, 64, 0, stream>>>(cnt, probsum, offs, cursor,
                                          out + (size_t)T_TOK * H_DIM);
    scatter_kernel<<<T_TOK / 256, 256, 0, stream>>>(tok_e, tok_w, cursor,
                                                    idx_list, wgt_list);
    if (compact) {
        dim3 g1(I_DIM / 64, T_TOK / 128, E_EXP);
        gemm1_mfma<<<g1, 256, 0, stream>>>(x, w1, w3, cnt, offs, idx_list, hdn, -1, 1);
        dim3 g2(H_DIM / 128, T_TOK / 128, E_EXP);
        gemm2_mfma<<<g2, 256, 0, stream>>>(hdn, w2, cnt, offs, idx_list, wgt_list,
                                           out, -1, 1);
    } else {
        for (int e = 0; e < E_EXP; e++) {
            gemm1_mfma<<<dim3(I_DIM / 64, T_TOK / 128, 1), 256, 0, stream>>>(
                x, w1, w3, cnt, offs, idx_list, hdn, e, 0);
            gemm2_mfma<<<dim3(H_DIM / 128, T_TOK / 128, 1), 256, 0, stream>>>(
                hdn, w2, cnt, offs, idx_list, wgt_list, out, e, 0);
        }
    }
}

// Round 4
// 1752.455 us; speedup vs baseline: 2.0490x; 1.0039x over previous
//
#include <hip/hip_runtime.h>
#include <hip/hip_bf16.h>
#include <math.h>

#define T_TOK 8192
#define H_DIM 1024
#define E_EXP 8
#define K_TOP 2
#define I_DIM 2048

typedef short bf16x8 __attribute__((ext_vector_type(8)));
typedef float f32x4 __attribute__((ext_vector_type(4)));

#define MFMA16(a, b, c) __builtin_amdgcn_mfma_f32_16x16x32_bf16((a), (b), (c), 0, 0, 0)

// LDS swizzle (units = shorts, row stride 32 shorts = 64B):
// XOR 16B-slot index with (row&7); bijective, applied on write AND read.
#define SWZ(r, k) ((((r) * 32) + (k)) ^ (((r) & 7) << 3))

__device__ __forceinline__ unsigned short f2bf(float f) {
    unsigned u = __builtin_bit_cast(unsigned, f);
    u += 0x7fffu + ((u >> 16) & 1u);          // RNE
    return (unsigned short)(u >> 16);
}
__device__ __forceinline__ float bf2f(unsigned short s) {
    return __builtin_bit_cast(float, ((unsigned)s) << 16);
}
__device__ __forceinline__ void split4(float4 v, unsigned* hi, unsigned* lo) {
    unsigned short hx = f2bf(v.x), hy = f2bf(v.y), hz = f2bf(v.z), hw = f2bf(v.w);
    unsigned short lx = f2bf(v.x - bf2f(hx)), ly = f2bf(v.y - bf2f(hy));
    unsigned short lz = f2bf(v.z - bf2f(hz)), lw = f2bf(v.w - bf2f(hw));
    hi[0] = (unsigned)hx | ((unsigned)hy << 16);
    hi[1] = (unsigned)hz | ((unsigned)hw << 16);
    lo[0] = (unsigned)lx | ((unsigned)ly << 16);
    lo[1] = (unsigned)lz | ((unsigned)lw << 16);
}

// ---------------------------------------------------------------------------
// Workspace layout (bytes):
//   0    : cnt[8] | 32: cursor[8] | 64: probsum[8] | 96: offs[8]
//   256  : tok_e[T*2] int | +64K: tok_w[T*2] f32
//   +64K : idx_list[T*K] int | +64K: wgt_list[T*K] f32
//   262400: TIER2: xh,xl | w1h,w1l,w3h,w3l,w2h,w2l | hdnh,hdnl  (352 MB)
//           TIER1 fallback: hdn fp32 [T*K][I] (134 MB)
// ---------------------------------------------------------------------------

__global__ __launch_bounds__(256) void gate_kernel(
    const float* __restrict__ xt, const float* __restrict__ gw,
    int* __restrict__ cnt, float* __restrict__ probsum,
    int* __restrict__ tok_e, float* __restrict__ tok_w)
{
    __shared__ float s_probs[4][8];
    __shared__ int   s_cnt[8];
    int tid = threadIdx.x;
    if (tid < 8) s_cnt[tid] = 0;
    __syncthreads();

    int wave = tid >> 6, lane = tid & 63;
    int t = blockIdx.x * 4 + wave;

    float acc[8];
#pragma unroll
    for (int e = 0; e < 8; e++) acc[e] = 0.f;
    const float* xrow = xt + (size_t)t * H_DIM;
    for (int k = lane; k < H_DIM; k += 64) {
        float xv = xrow[k];
#pragma unroll
        for (int e = 0; e < 8; e++) acc[e] = fmaf(xv, gw[e * H_DIM + k], acc[e]);
    }
#pragma unroll
    for (int off = 32; off > 0; off >>= 1) {
#pragma unroll
        for (int e = 0; e < 8; e++) acc[e] += __shfl_down(acc[e], off);
    }
    if (lane == 0) {
        float mx = acc[0];
#pragma unroll
        for (int e = 1; e < 8; e++) mx = fmaxf(mx, acc[e]);
        float p[8]; float sum = 0.f;
#pragma unroll
        for (int e = 0; e < 8; e++) { p[e] = expf(acc[e] - mx); sum += p[e]; }
        float inv = 1.f / sum;
#pragma unroll
        for (int e = 0; e < 8; e++) p[e] *= inv;
        int i0 = 0;
#pragma unroll
        for (int e = 1; e < 8; e++) if (p[e] > p[i0]) i0 = e;
        int i1 = (i0 == 0) ? 1 : 0;
#pragma unroll
        for (int e = 0; e < 8; e++) if (e != i0 && p[e] > p[i1]) i1 = e;
        float w0 = p[i0], w1v = p[i1];
        float denom = w0 + w1v + 1e-6f;
        tok_e[t * 2 + 0] = i0;            tok_e[t * 2 + 1] = i1;
        tok_w[t * 2 + 0] = w0 / denom;    tok_w[t * 2 + 1] = w1v / denom;
        atomicAdd(&s_cnt[i0], 1);
        atomicAdd(&s_cnt[i1], 1);
#pragma unroll
        for (int e = 0; e < 8; e++) s_probs[wave][e] = p[e];
    }
    __syncthreads();
    if (tid < 8) {
        float s = s_probs[0][tid] + s_probs[1][tid] + s_probs[2][tid] + s_probs[3][tid];
        atomicAdd(&probsum[tid], s);
        if (s_cnt[tid]) atomicAdd(&cnt[tid], s_cnt[tid]);
    }
}

__global__ void offs_aux_kernel(const int* __restrict__ cnt,
                                const float* __restrict__ probsum,
                                int* __restrict__ offs, int* __restrict__ cursor,
                                float* __restrict__ out_aux)
{
    if (threadIdx.x == 0 && blockIdx.x == 0) {
        int o = 0; float aux = 0.f;
        for (int e = 0; e < E_EXP; e++) {
            offs[e] = o; cursor[e] = o; o += cnt[e];
            aux += (float)cnt[e] * probsum[e];
        }
        out_aux[0] = aux * (float)E_EXP / ((float)T_TOK * (float)T_TOK);
    }
}

__global__ __launch_bounds__(256) void scatter_kernel(
    const int* __restrict__ tok_e, const float* __restrict__ tok_w,
    int* __restrict__ cursor, int* __restrict__ idx_list, float* __restrict__ wgt_list)
{
    int t = blockIdx.x * 256 + threadIdx.x;
#pragma unroll
    for (int s = 0; s < K_TOP; s++) {
        int e = tok_e[t * 2 + s];
        int pos = atomicAdd(&cursor[e], 1);
        idx_list[pos] = t;
        wgt_list[pos] = tok_w[t * 2 + s];
    }
}

// fp32 -> (bf16 hi plane, bf16 lo plane), 8 elems (one 16B chunk/plane) per iter
__global__ __launch_bounds__(256) void convert_split_kernel(
    const float4* __restrict__ src, uint4* __restrict__ hi, uint4* __restrict__ lo,
    int nchunk)
{
    int stride = gridDim.x * blockDim.x;
    for (int c = blockIdx.x * blockDim.x + threadIdx.x; c < nchunk; c += stride) {
        float4 a = src[2 * c + 0];
        float4 b = src[2 * c + 1];
        unsigned h[4], l[4];
        split4(a, &h[0], &l[0]);
        split4(b, &h[2], &l[2]);
        hi[c] = make_uint4(h[0], h[1], h[2], h[3]);
        lo[c] = make_uint4(l[0], l[1], l[2], l[3]);
    }
}

// ---------------------------------------------------------------------------
// TIER2 GEMM1: pre-split operands. tile 128x64, BK=32, 4 waves 2x2
// ---------------------------------------------------------------------------
__global__ __launch_bounds__(256) void gemm1_pre(
    const unsigned short* __restrict__ xh, const unsigned short* __restrict__ xl,
    const unsigned short* __restrict__ w1h, const unsigned short* __restrict__ w1l,
    const unsigned short* __restrict__ w3h, const unsigned short* __restrict__ w3l,
    const int* __restrict__ cnt, const int* __restrict__ offs,
    const int* __restrict__ idx_list,
    unsigned short* __restrict__ hdnh, unsigned short* __restrict__ hdnl)
{
    int e = blockIdx.z;
    int n_e = cnt[e];
    int row0 = blockIdx.y * 128;
    if (row0 >= n_e) return;
    int col0 = blockIdx.x * 64;
    int lbase = offs[e];

    __shared__ unsigned short Ah[128 * 32], Al[128 * 32];
    __shared__ unsigned short B1h[64 * 32], B1l[64 * 32];
    __shared__ unsigned short B3h[64 * 32], B3l[64 * 32];
    __shared__ int toks[128];

    int tid = threadIdx.x;
    if (tid < 128) {
        int r = row0 + tid;
        toks[tid] = (r < n_e) ? idx_list[lbase + r] : -1;
    }
    __syncthreads();

    const size_t wbase = (size_t)e * I_DIM * H_DIM;

    f32x4 accu[4][2], accv[4][2];
#pragma unroll
    for (int i = 0; i < 4; i++)
#pragma unroll
        for (int j = 0; j < 2; j++) { accu[i][j] = (f32x4)(0.f); accv[i][j] = (f32x4)(0.f); }

    int lane = tid & 63, wid = tid >> 6;
    int wm = wid >> 1, wn = wid & 1;
    int lr = lane & 15, lq = lane >> 4;
    const bf16x8 zero8 = {0, 0, 0, 0, 0, 0, 0, 0};

    for (int k0 = 0; k0 < H_DIM; k0 += 32) {
        // A: 128x32 per plane, 16B chunks, 2 per thread per plane
#pragma unroll
        for (int p = 0; p < 2; p++) {
            int c = tid + p * 256;
            int row = c >> 2, kh = (c & 3) * 8;
            int tok = toks[row];
            bf16x8 vh = zero8, vl = zero8;
            if (tok >= 0) {
                size_t g = (size_t)tok * H_DIM + k0 + kh;
                vh = *(const bf16x8*)&xh[g];
                vl = *(const bf16x8*)&xl[g];
            }
            int s = SWZ(row, kh);
            *(bf16x8*)&Ah[s] = vh;
            *(bf16x8*)&Al[s] = vl;
        }
        // B: 64x32 per plane, 1 chunk per thread per plane
        {
            int row = tid >> 2, kh = (tid & 3) * 8;
            size_t g = wbase + (size_t)(col0 + row) * H_DIM + k0 + kh;
            int s = SWZ(row, kh);
            *(bf16x8*)&B1h[s] = *(const bf16x8*)&w1h[g];
            *(bf16x8*)&B1l[s] = *(const bf16x8*)&w1l[g];
            *(bf16x8*)&B3h[s] = *(const bf16x8*)&w3h[g];
            *(bf16x8*)&B3l[s] = *(const bf16x8*)&w3l[g];
        }
        __syncthreads();

        bf16x8 ah[4], al[4];
#pragma unroll
        for (int i = 0; i < 4; i++) {
            int r = wm * 64 + i * 16 + lr;
            int s = SWZ(r, lq * 8);
            ah[i] = *(const bf16x8*)&Ah[s];
            al[i] = *(const bf16x8*)&Al[s];
        }
#pragma unroll
        for (int j = 0; j < 2; j++) {
            int rb = wn * 32 + j * 16 + lr;
            int s = SWZ(rb, lq * 8);
            bf16x8 b1h = *(const bf16x8*)&B1h[s];
            bf16x8 b1l = *(const bf16x8*)&B1l[s];
            bf16x8 b3h = *(const bf16x8*)&B3h[s];
            bf16x8 b3l = *(const bf16x8*)&B3l[s];
#pragma unroll
            for (int i = 0; i < 4; i++) {
                accu[i][j] = MFMA16(ah[i], b1h, accu[i][j]);
                accu[i][j] = MFMA16(ah[i], b1l, accu[i][j]);
                accu[i][j] = MFMA16(al[i], b1h, accu[i][j]);
                accv[i][j] = MFMA16(ah[i], b3h, accv[i][j]);
                accv[i][j] = MFMA16(ah[i], b3l, accv[i][j]);
                accv[i][j] = MFMA16(al[i], b3h, accv[i][j]);
            }
        }
        __syncthreads();
    }

#pragma unroll
    for (int i = 0; i < 4; i++) {
#pragma unroll
        for (int r = 0; r < 4; r++) {
            int lrow = wm * 64 + i * 16 + lq * 4 + r;
            int grow = row0 + lrow;
            if (grow < n_e) {
                size_t base = (size_t)(lbase + grow) * I_DIM + col0;
#pragma unroll
                for (int j = 0; j < 2; j++) {
                    float u = accu[i][j][r], v = accv[i][j][r];
                    float si = u / (1.f + expf(-u));
                    float val = si * v;
                    unsigned short h = f2bf(val);
                    unsigned short l = f2bf(val - bf2f(h));
                    int cidx = wn * 32 + j * 16 + lr;
                    hdnh[base + cidx] = h;
                    hdnl[base + cidx] = l;
                }
            }
        }
    }
}

// ---------------------------------------------------------------------------
// TIER2 GEMM2: tile 128x128 over H, BK=32, 4 waves 2x2; atomic combine
// ---------------------------------------------------------------------------
__global__ __launch_bounds__(256) void gemm2_pre(
    const unsigned short* __restrict__ hdnh, const unsigned short* __restrict__ hdnl,
    const unsigned short* __restrict__ w2h, const unsigned short* __restrict__ w2l,
    const int* __restrict__ cnt, const int* __restrict__ offs,
    const int* __restrict__ idx_list, const float* __restrict__ wgt_list,
    float* __restrict__ out)
{
    int e = blockIdx.z;
    int n_e = cnt[e];
    int row0 = blockIdx.y * 128;
    if (row0 >= n_e) return;
    int col0 = blockIdx.x * 128;
    int lbase = offs[e];

    __shared__ unsigned short Ah[128 * 32], Al[128 * 32];
    __shared__ unsigned short Bh[128 * 32], Bl[128 * 32];
    __shared__ int   s_tok[128];
    __shared__ float s_wgt[128];

    int tid = threadIdx.x;
    if (tid < 128) {
        int r = row0 + tid;
        s_tok[tid] = (r < n_e) ? idx_list[lbase + r] : -1;
        s_wgt[tid] = (r < n_e) ? wgt_list[lbase + r] : 0.f;
    }

    const size_t wbase = (size_t)e * H_DIM * I_DIM;

    f32x4 acc[4][4];
#pragma unroll
    for (int i = 0; i < 4; i++)
#pragma unroll
        for (int j = 0; j < 4; j++) acc[i][j] = (f32x4)(0.f);

    int lane = tid & 63, wid = tid >> 6;
    int wm = wid >> 1, wn = wid & 1;
    int lr = lane & 15, lq = lane >> 4;
    const bf16x8 zero8 = {0, 0, 0, 0, 0, 0, 0, 0};

    for (int k0 = 0; k0 < I_DIM; k0 += 32) {
#pragma unroll
        for (int p = 0; p < 2; p++) {
            int c = tid + p * 256;
            int row = c >> 2, kh = (c & 3) * 8;
            bf16x8 vh = zero8, vl = zero8;
            if (row0 + row < n_e) {
                size_t g = (size_t)(lbase + row0 + row) * I_DIM + k0 + kh;
                vh = *(const bf16x8*)&hdnh[g];
                vl = *(const bf16x8*)&hdnl[g];
            }
            int s = SWZ(row, kh);
            *(bf16x8*)&Ah[s] = vh;
            *(bf16x8*)&Al[s] = vl;
        }
#pragma unroll
        for (int p = 0; p < 2; p++) {
            int c = tid + p * 256;
            int row = c >> 2, kh = (c & 3) * 8;
            size_t g = wbase + (size_t)(col0 + row) * I_DIM + k0 + kh;
            int s = SWZ(row, kh);
            *(bf16x8*)&Bh[s] = *(const bf16x8*)&w2h[g];
            *(bf16x8*)&Bl[s] = *(const bf16x8*)&w2l[g];
        }
        __syncthreads();

        bf16x8 ah[4], al[4];
#pragma unroll
        for (int i = 0; i < 4; i++) {
            int r = wm * 64 + i * 16 + lr;
            int s = SWZ(r, lq * 8);
            ah[i] = *(const bf16x8*)&Ah[s];
            al[i] = *(const bf16x8*)&Al[s];
        }
#pragma unroll
        for (int j = 0; j < 4; j++) {
            int rb = wn * 64 + j * 16 + lr;
            int s = SWZ(rb, lq * 8);
            bf16x8 bh = *(const bf16x8*)&Bh[s];
            bf16x8 bl = *(const bf16x8*)&Bl[s];
#pragma unroll
            for (int i = 0; i < 4; i++) {
                acc[i][j] = MFMA16(ah[i], bh, acc[i][j]);
                acc[i][j] = MFMA16(ah[i], bl, acc[i][j]);
                acc[i][j] = MFMA16(al[i], bh, acc[i][j]);
            }
        }
        __syncthreads();
    }

#pragma unroll
    for (int i = 0; i < 4; i++) {
#pragma unroll
        for (int r = 0; r < 4; r++) {
            int lrow = wm * 64 + i * 16 + lq * 4 + r;
            int grow = row0 + lrow;
            if (grow < n_e) {
                int t = s_tok[lrow];
                float wt = s_wgt[lrow];
                float* orow = out + (size_t)t * H_DIM + col0;
#pragma unroll
                for (int j = 0; j < 4; j++)
                    atomicAdd(&orow[wn * 64 + j * 16 + lr], wt * acc[i][j][r]);
            }
        }
    }
}

// ---------------------------------------------------------------------------
// TIER1/0 fallback (round-3 kernels, on-the-fly split, fp32 hdn)
// ---------------------------------------------------------------------------
__global__ __launch_bounds__(256) void gemm1_mfma(
    const float* __restrict__ xt, const float* __restrict__ w1,
    const float* __restrict__ w3,
    const int* __restrict__ cnt, const int* __restrict__ offs,
    const int* __restrict__ idx_list,
    float* __restrict__ hdn, int e_param, int compact)
{
    int e = (e_param >= 0) ? e_param : (int)blockIdx.z;
    int n_e = cnt[e];
    int row0 = blockIdx.y * 128;
    if (row0 >= n_e) return;
    int col0 = blockIdx.x * 64;
    int lbase = offs[e];
    size_t hbase = compact ? (size_t)lbase : 0;

    __shared__ unsigned short Ah[128 * 32], Al[128 * 32];
    __shared__ unsigned short B1h[64 * 32], B1l[64 * 32];
    __shared__ unsigned short B3h[64 * 32], B3l[64 * 32];
    __shared__ int toks[128];

    int tid = threadIdx.x;
    if (tid < 128) {
        int r = row0 + tid;
        toks[tid] = (r < n_e) ? idx_list[lbase + r] : -1;
    }
    __syncthreads();

    const float* w1e = w1 + (size_t)e * I_DIM * H_DIM;
    const float* w3e = w3 + (size_t)e * I_DIM * H_DIM;

    f32x4 accu[4][2], accv[4][2];
#pragma unroll
    for (int i = 0; i < 4; i++)
#pragma unroll
        for (int j = 0; j < 2; j++) { accu[i][j] = (f32x4)(0.f); accv[i][j] = (f32x4)(0.f); }

    int lane = tid & 63, wid = tid >> 6;
    int wm = wid >> 1, wn = wid & 1;
    int lr = lane & 15, lq = lane >> 4;

    for (int k0 = 0; k0 < H_DIM; k0 += 32) {
#pragma unroll
        for (int p = 0; p < 4; p++) {
            int idx = tid + p * 256;
            int row = idx >> 3, kq = (idx & 7) << 2;
            int tok = toks[row];
            float4 v = (tok >= 0)
                ? *(const float4*)&xt[(size_t)tok * H_DIM + k0 + kq]
                : make_float4(0.f, 0.f, 0.f, 0.f);
            unsigned hi[2], lo[2];
            split4(v, hi, lo);
            int s = SWZ(row, kq);
            *(uint2*)&Ah[s] = make_uint2(hi[0], hi[1]);
            *(uint2*)&Al[s] = make_uint2(lo[0], lo[1]);
        }
#pragma unroll
        for (int p = 0; p < 2; p++) {
            int idx = tid + p * 256;
            int row = idx >> 3, kq = (idx & 7) << 2;
            size_t goff = (size_t)(col0 + row) * H_DIM + k0 + kq;
            float4 v1 = *(const float4*)&w1e[goff];
            float4 v3 = *(const float4*)&w3e[goff];
            unsigned hi[2], lo[2];
            int s = SWZ(row, kq);
            split4(v1, hi, lo);
            *(uint2*)&B1h[s] = make_uint2(hi[0], hi[1]);
            *(uint2*)&B1l[s] = make_uint2(lo[0], lo[1]);
            split4(v3, hi, lo);
            *(uint2*)&B3h[s] = make_uint2(hi[0], hi[1]);
            *(uint2*)&B3l[s] = make_uint2(lo[0], lo[1]);
        }
        __syncthreads();

        bf16x8 ah[4], al[4];
#pragma unroll
        for (int i = 0; i < 4; i++) {
            int r = wm * 64 + i * 16 + lr;
            int s = SWZ(r, lq * 8);
            ah[i] = *(const bf16x8*)&Ah[s];
            al[i] = *(const bf16x8*)&Al[s];
        }
#pragma unroll
        for (int j = 0; j < 2; j++) {
            int rb = wn * 32 + j * 16 + lr;
            int s = SWZ(rb, lq * 8);
            bf16x8 b1h = *(const bf16x8*)&B1h[s];
            bf16x8 b1l = *(const bf16x8*)&B1l[s];
            bf16x8 b3h = *(const bf16x8*)&B3h[s];
            bf16x8 b3l = *(const bf16x8*)&B3l[s];
#pragma unroll
            for (int i = 0; i < 4; i++) {
                accu[i][j] = MFMA16(ah[i], b1h, accu[i][j]);
                accu[i][j] = MFMA16(ah[i], b1l, accu[i][j]);
                accu[i][j] = MFMA16(al[i], b1h, accu[i][j]);
                accv[i][j] = MFMA16(ah[i], b3h, accv[i][j]);
                accv[i][j] = MFMA16(ah[i], b3l, accv[i][j]);
                accv[i][j] = MFMA16(al[i], b3h, accv[i][j]);
            }
        }
        __syncthreads();
    }

#pragma unroll
    for (int i = 0; i < 4; i++) {
#pragma unroll
        for (int r = 0; r < 4; r++) {
            int lrow = wm * 64 + i * 16 + lq * 4 + r;
            int grow = row0 + lrow;
            if (grow < n_e) {
                float* hrow = hdn + (hbase + grow) * (size_t)I_DIM + col0;
#pragma unroll
                for (int j = 0; j < 2; j++) {
                    float u = accu[i][j][r];
                    float v = accv[i][j][r];
                    float si = u / (1.f + expf(-u));
                    hrow[wn * 32 + j * 16 + lr] = si * v;
                }
            }
        }
    }
}

__global__ __launch_bounds__(256) void gemm2_mfma(
    const float* __restrict__ hdn, const float* __restrict__ w2,
    const int* __restrict__ cnt, const int* __restrict__ offs,
    const int* __restrict__ idx_list, const float* __restrict__ wgt_list,
    float* __restrict__ out, int e_param, int compact)
{
    int e = (e_param >= 0) ? e_param : (int)blockIdx.z;
    int n_e = cnt[e];
    int row0 = blockIdx.y * 128;
    if (row0 >= n_e) return;
    int col0 = blockIdx.x * 128;
    int lbase = offs[e];
    size_t hbase = compact ? (size_t)lbase : 0;

    __shared__ unsigned short Ah[128 * 32], Al[128 * 32];
    __shared__ unsigned short Bh[128 * 32], Bl[128 * 32];
    __shared__ int   s_tok[128];
    __shared__ float s_wgt[128];

    int tid = threadIdx.x;
    if (tid < 128) {
        int r = row0 + tid;
        s_tok[tid] = (r < n_e) ? idx_list[lbase + r] : -1;
        s_wgt[tid] = (r < n_e) ? wgt_list[lbase + r] : 0.f;
    }

    const float* w2e = w2 + (size_t)e * H_DIM * I_DIM;

    f32x4 acc[4][4];
#pragma unroll
    for (int i = 0; i < 4; i++)
#pragma unroll
        for (int j = 0; j < 4; j++) acc[i][j] = (f32x4)(0.f);

    int lane = tid & 63, wid = tid >> 6;
    int wm = wid >> 1, wn = wid & 1;
    int lr = lane & 15, lq = lane >> 4;

    for (int k0 = 0; k0 < I_DIM; k0 += 32) {
#pragma unroll
        for (int p = 0; p < 4; p++) {
            int idx = tid + p * 256;
            int row = idx >> 3, kq = (idx & 7) << 2;
            float4 v = (row0 + row < n_e)
                ? *(const float4*)&hdn[(hbase + row0 + row) * (size_t)I_DIM + k0 + kq]
                : make_float4(0.f, 0.f, 0.f, 0.f);
            unsigned hi[2], lo[2];
            split4(v, hi, lo);
            int s = SWZ(row, kq);
            *(uint2*)&Ah[s] = make_uint2(hi[0], hi[1]);
            *(uint2*)&Al[s] = make_uint2(lo[0], lo[1]);
        }
#pragma unroll
        for (int p = 0; p < 4; p++) {
            int idx = tid + p * 256;
            int row = idx >> 3, kq = (idx & 7) << 2;
            float4 v = *(const float4*)&w2e[(size_t)(col0 + row) * I_DIM + k0 + kq];
            unsigned hi[2], lo[2];
            split4(v, hi, lo);
            int s = SWZ(row, kq);
            *(uint2*)&Bh[s] = make_uint2(hi[0], hi[1]);
            *(uint2*)&Bl[s] = make_uint2(lo[0], lo[1]);
        }
        __syncthreads();

        bf16x8 ah[4], al[4];
#pragma unroll
        for (int i = 0; i < 4; i++) {
            int r = wm * 64 + i * 16 + lr;
            int s = SWZ(r, lq * 8);
            ah[i] = *(const bf16x8*)&Ah[s];
            al[i] = *(const bf16x8*)&Al[s];
        }
#pragma unroll
        for (int j = 0; j < 4; j++) {
            int rb = wn * 64 + j * 16 + lr;
            int s = SWZ(rb, lq * 8);
            bf16x8 bh = *(const bf16x8*)&Bh[s];
            bf16x8 bl = *(const bf16x8*)&Bl[s];
#pragma unroll
            for (int i = 0; i < 4; i++) {
                acc[i][j] = MFMA16(ah[i], bh, acc[i][j]);
                acc[i][j] = MFMA16(ah[i], bl, acc[i][j]);
                acc[i][j] = MFMA16(al[i], bh, acc[i][j]);
            }
        }
        __syncthreads();
    }

#pragma unroll
    for (int i = 0; i < 4; i++) {
#pragma unroll
        for (int r = 0; r < 4; r++) {
            int lrow = wm * 64 + i * 16 + lq * 4 + r;
            int grow = row0 + lrow;
            if (grow < n_e) {
                int t = s_tok[lrow];
                float wt = s_wgt[lrow];
                float* orow = out + (size_t)t * H_DIM + col0;
#pragma unroll
                for (int j = 0; j < 4; j++)
                    atomicAdd(&orow[wn * 64 + j * 16 + lr], wt * acc[i][j][r]);
            }
        }
    }
}

extern "C" void kernel_launch(void* const* d_in, const int* in_sizes, int n_in,
                              void* d_out, int out_size, void* d_ws, size_t ws_size,
                              hipStream_t stream) {
    const float* x  = (const float*)d_in[0];
    const float* gw = (const float*)d_in[1];
    const float* w1 = (const float*)d_in[2];
    const float* w2 = (const float*)d_in[3];
    const float* w3 = (const float*)d_in[4];
    float* out = (float*)d_out;

    char* ws = (char*)d_ws;
    int*   cnt      = (int*)(ws + 0);
    int*   cursor   = (int*)(ws + 32);
    float* probsum  = (float*)(ws + 64);
    int*   offs     = (int*)(ws + 96);
    int*   tok_e    = (int*)(ws + 256);
    float* tok_w    = (float*)(ws + 256 + 65536);
    int*   idx_list = (int*)(ws + 256 + 2 * 65536);
    float* wgt_list = (float*)(ws + 256 + 3 * 65536);
    size_t buf0     = 256 + 4 * 65536;     // 262400, 256-aligned

    // tier-2 layout
    const size_t XB = (size_t)T_TOK * H_DIM * 2;          // 16.78 MB
    const size_t WB = (size_t)E_EXP * I_DIM * H_DIM * 2;  // 33.55 MB
    const size_t DB = (size_t)T_TOK * K_TOP * I_DIM * 2;  // 67.1 MB
    size_t off = buf0;
    size_t xh_o = off;  off += XB;   size_t xl_o = off;  off += XB;
    size_t w1h_o = off; off += WB;   size_t w1l_o = off; off += WB;
    size_t w3h_o = off; off += WB;   size_t w3l_o = off; off += WB;
    size_t w2h_o = off; off += WB;   size_t w2l_o = off; off += WB;
    size_t dh_o = off;  off += DB;   size_t dl_o = off;  off += DB;
    size_t need2 = off;
    size_t need1 = buf0 + (size_t)T_TOK * K_TOP * I_DIM * sizeof(float);

    hipMemsetAsync(ws, 0, 128, stream);
    hipMemsetAsync(d_out, 0, (size_t)T_TOK * H_DIM * sizeof(float), stream);

    gate_kernel<<<T_TOK / 4, 256, 0, stream>>>(x, gw, cnt, probsum, tok_e, tok_w);
    offs_aux_kernel<<<1, 64, 0, stream>>>(cnt, probsum, offs, cursor,
                                          out + (size_t)T_TOK * H_DIM);
    scatter_kernel<<<T_TOK / 256, 256, 0, stream>>>(tok_e, tok_w, cursor,
                                                    idx_list, wgt_list);

    if (ws_size >= need2) {
        const int wchunk = E_EXP * I_DIM * H_DIM / 8;   // 2,097,152
        const int xchunk = T_TOK * H_DIM / 8;           // 1,048,576
        convert_split_kernel<<<2048, 256, 0, stream>>>(
            (const float4*)w1, (uint4*)(ws + w1h_o), (uint4*)(ws + w1l_o), wchunk);
        convert_split_kernel<<<2048, 256, 0, stream>>>(
            (const float4*)w3, (uint4*)(ws + w3h_o), (uint4*)(ws + w3l_o), wchunk);
        convert_split_kernel<<<2048, 256, 0, stream>>>(
            (const float4*)w2, (uint4*)(ws + w2h_o), (uint4*)(ws + w2l_o), wchunk);
        convert_split_kernel<<<2048, 256, 0, stream>>>(
            (const float4*)x, (uint4*)(ws + xh_o), (uint4*)(ws + xl_o), xchunk);

        dim3 g1(I_DIM / 64, T_TOK / 128, E_EXP);
        gemm1_pre<<<g1, 256, 0, stream>>>(
            (const unsigned short*)(ws + xh_o), (const unsigned short*)(ws + xl_o),
            (const unsigned short*)(ws + w1h_o), (const unsigned short*)(ws + w1l_o),
            (const unsigned short*)(ws + w3h_o), (const unsigned short*)(ws + w3l_o),
            cnt, offs, idx_list,
            (unsigned short*)(ws + dh_o), (unsigned short*)(ws + dl_o));
        dim3 g2(H_DIM / 128, T_TOK / 128, E_EXP);
        gemm2_pre<<<g2, 256, 0, stream>>>(
            (const unsigned short*)(ws + dh_o), (const unsigned short*)(ws + dl_o),
            (const unsigned short*)(ws + w2h_o), (const unsigned short*)(ws + w2l_o),
            cnt, offs, idx_list, wgt_list, out);
    } else if (ws_size >= need1) {
        float* hdn = (float*)(ws + buf0);
        dim3 g1(I_DIM / 64, T_TOK / 128, E_EXP);
        gemm1_mfma<<<g1, 256, 0, stream>>>(x, w1, w3, cnt, offs, idx_list, hdn, -1, 1);
        dim3 g2(H_DIM / 128, T_TOK / 128, E_EXP);
        gemm2_mfma<<<g2, 256, 0, stream>>>(hdn, w2, cnt, offs, idx_list, wgt_list,
                                           out, -1, 1);
    } else {
        float* hdn = (float*)(ws + buf0);
        for (int e = 0; e < E_EXP; e++) {
            gemm1_mfma<<<dim3(I_DIM / 64, T_TOK / 128, 1), 256, 0, stream>>>(
                x, w1, w3, cnt, offs, idx_list, hdn, e, 0);
            gemm2_mfma<<<dim3(H_DIM / 128, T_TOK / 128, 1), 256, 0, stream>>>(
                hdn, w2, cnt, offs, idx_list, wgt_list, out, e, 0);
        }
    }
}

// Round 5
// 1609.055 us; speedup vs baseline: 2.2316x; 1.0891x over previous
//
#include <hip/hip_runtime.h>
#include <hip/hip_bf16.h>
#include <math.h>

#define T_TOK 8192
#define H_DIM 1024
#define E_EXP 8
#define K_TOP 2
#define I_DIM 2048

typedef short bf16x8 __attribute__((ext_vector_type(8)));
typedef float f32x4 __attribute__((ext_vector_type(4)));

#define MFMA16(a, b, c) __builtin_amdgcn_mfma_f32_16x16x32_bf16((a), (b), (c), 0, 0, 0)

// LDS swizzle (units = shorts, row stride 32 shorts = 64B):
// XOR 16B-slot index with (row&7); bijective, applied on write AND read.
#define SWZ(r, k) ((((r) * 32) + (k)) ^ (((r) & 7) << 3))

__device__ __forceinline__ unsigned short f2bf(float f) {
    unsigned u = __builtin_bit_cast(unsigned, f);
    u += 0x7fffu + ((u >> 16) & 1u);          // RNE
    return (unsigned short)(u >> 16);
}
__device__ __forceinline__ float bf2f(unsigned short s) {
    return __builtin_bit_cast(float, ((unsigned)s) << 16);
}
__device__ __forceinline__ void split4(float4 v, unsigned* hi, unsigned* lo) {
    unsigned short hx = f2bf(v.x), hy = f2bf(v.y), hz = f2bf(v.z), hw = f2bf(v.w);
    unsigned short lx = f2bf(v.x - bf2f(hx)), ly = f2bf(v.y - bf2f(hy));
    unsigned short lz = f2bf(v.z - bf2f(hz)), lw = f2bf(v.w - bf2f(hw));
    hi[0] = (unsigned)hx | ((unsigned)hy << 16);
    hi[1] = (unsigned)hz | ((unsigned)hw << 16);
    lo[0] = (unsigned)lx | ((unsigned)ly << 16);
    lo[1] = (unsigned)lz | ((unsigned)lw << 16);
}

// ---------------------------------------------------------------------------
// Workspace (bytes):
//   0: cnt[8] | 32: cursor[8] | 64: probsum[8] | 96: offs[8]
//   256: tok_e | +64K: tok_w | +64K: idx_list | +64K: wgt_list
//   buf0 (262400):
//     PS tier: xh,xl (33.5MB) | wslot (4*EG*4.19MB, w2 aliases) | hdnh,hdnl (134.2MB)
//     fallback tier: hdn fp32 compact (134.2MB)
// ---------------------------------------------------------------------------

__global__ __launch_bounds__(256) void gate_kernel(
    const float* __restrict__ xt, const float* __restrict__ gw,
    int* __restrict__ cnt, float* __restrict__ probsum,
    int* __restrict__ tok_e, float* __restrict__ tok_w)
{
    __shared__ float s_probs[4][8];
    __shared__ int   s_cnt[8];
    int tid = threadIdx.x;
    if (tid < 8) s_cnt[tid] = 0;
    __syncthreads();

    int wave = tid >> 6, lane = tid & 63;
    int t = blockIdx.x * 4 + wave;

    float acc[8];
#pragma unroll
    for (int e = 0; e < 8; e++) acc[e] = 0.f;
    const float* xrow = xt + (size_t)t * H_DIM;
    for (int k = lane; k < H_DIM; k += 64) {
        float xv = xrow[k];
#pragma unroll
        for (int e = 0; e < 8; e++) acc[e] = fmaf(xv, gw[e * H_DIM + k], acc[e]);
    }
#pragma unroll
    for (int off = 32; off > 0; off >>= 1) {
#pragma unroll
        for (int e = 0; e < 8; e++) acc[e] += __shfl_down(acc[e], off);
    }
    if (lane == 0) {
        float mx = acc[0];
#pragma unroll
        for (int e = 1; e < 8; e++) mx = fmaxf(mx, acc[e]);
        float p[8]; float sum = 0.f;
#pragma unroll
        for (int e = 0; e < 8; e++) { p[e] = expf(acc[e] - mx); sum += p[e]; }
        float inv = 1.f / sum;
#pragma unroll
        for (int e = 0; e < 8; e++) p[e] *= inv;
        int i0 = 0;
#pragma unroll
        for (int e = 1; e < 8; e++) if (p[e] > p[i0]) i0 = e;
        int i1 = (i0 == 0) ? 1 : 0;
#pragma unroll
        for (int e = 0; e < 8; e++) if (e != i0 && p[e] > p[i1]) i1 = e;
        float w0 = p[i0], w1v = p[i1];
        float denom = w0 + w1v + 1e-6f;
        tok_e[t * 2 + 0] = i0;            tok_e[t * 2 + 1] = i1;
        tok_w[t * 2 + 0] = w0 / denom;    tok_w[t * 2 + 1] = w1v / denom;
        atomicAdd(&s_cnt[i0], 1);
        atomicAdd(&s_cnt[i1], 1);
#pragma unroll
        for (int e = 0; e < 8; e++) s_probs[wave][e] = p[e];
    }
    __syncthreads();
    if (tid < 8) {
        float s = s_probs[0][tid] + s_probs[1][tid] + s_probs[2][tid] + s_probs[3][tid];
        atomicAdd(&probsum[tid], s);
        if (s_cnt[tid]) atomicAdd(&cnt[tid], s_cnt[tid]);
    }
}

__global__ void offs_aux_kernel(const int* __restrict__ cnt,
                                const float* __restrict__ probsum,
                                int* __restrict__ offs, int* __restrict__ cursor,
                                float* __restrict__ out_aux)
{
    if (threadIdx.x == 0 && blockIdx.x == 0) {
        int o = 0; float aux = 0.f;
        for (int e = 0; e < E_EXP; e++) {
            offs[e] = o; cursor[e] = o; o += cnt[e];
            aux += (float)cnt[e] * probsum[e];
        }
        out_aux[0] = aux * (float)E_EXP / ((float)T_TOK * (float)T_TOK);
    }
}

__global__ __launch_bounds__(256) void scatter_kernel(
    const int* __restrict__ tok_e, const float* __restrict__ tok_w,
    int* __restrict__ cursor, int* __restrict__ idx_list, float* __restrict__ wgt_list)
{
    int t = blockIdx.x * 256 + threadIdx.x;
#pragma unroll
    for (int s = 0; s < K_TOP; s++) {
        int e = tok_e[t * 2 + s];
        int pos = atomicAdd(&cursor[e], 1);
        idx_list[pos] = t;
        wgt_list[pos] = tok_w[t * 2 + s];
    }
}

// fp32 -> (bf16 hi plane, bf16 lo plane), 8 elems/iter
__global__ __launch_bounds__(256) void convert_split_kernel(
    const float4* __restrict__ src, uint4* __restrict__ hi, uint4* __restrict__ lo,
    int nchunk)
{
    int stride = gridDim.x * blockDim.x;
    for (int c = blockIdx.x * blockDim.x + threadIdx.x; c < nchunk; c += stride) {
        float4 a = src[2 * c + 0];
        float4 b = src[2 * c + 1];
        unsigned h[4], l[4];
        split4(a, &h[0], &l[0]);
        split4(b, &h[2], &l[2]);
        hi[c] = make_uint4(h[0], h[1], h[2], h[3]);
        lo[c] = make_uint4(l[0], l[1], l[2], l[3]);
    }
}

// ---------------------------------------------------------------------------
// PS GEMM1: all operands pre-split. tile 128x64, BK=32, 4 waves 2x2
// weights are slot-relative (z = blockIdx.z within group); e = ebase+z
// ---------------------------------------------------------------------------
__global__ __launch_bounds__(256) void gemm1_ps(
    const unsigned short* __restrict__ xh, const unsigned short* __restrict__ xl,
    const unsigned short* __restrict__ w1h, const unsigned short* __restrict__ w1l,
    const unsigned short* __restrict__ w3h, const unsigned short* __restrict__ w3l,
    const int* __restrict__ cnt, const int* __restrict__ offs,
    const int* __restrict__ idx_list,
    unsigned short* __restrict__ hdnh, unsigned short* __restrict__ hdnl, int ebase)
{
    int z = blockIdx.z;
    int e = ebase + z;
    int n_e = cnt[e];
    int row0 = blockIdx.y * 128;
    if (row0 >= n_e) return;
    int col0 = blockIdx.x * 64;
    int lbase = offs[e];

    __shared__ unsigned short Ah[128 * 32], Al[128 * 32];
    __shared__ unsigned short B1h[64 * 32], B1l[64 * 32];
    __shared__ unsigned short B3h[64 * 32], B3l[64 * 32];
    __shared__ int toks[128];

    int tid = threadIdx.x;
    if (tid < 128) {
        int r = row0 + tid;
        toks[tid] = (r < n_e) ? idx_list[lbase + r] : -1;
    }
    __syncthreads();

    const size_t wbase = (size_t)z * I_DIM * H_DIM;

    f32x4 accu[4][2], accv[4][2];
#pragma unroll
    for (int i = 0; i < 4; i++)
#pragma unroll
        for (int j = 0; j < 2; j++) { accu[i][j] = (f32x4)(0.f); accv[i][j] = (f32x4)(0.f); }

    int lane = tid & 63, wid = tid >> 6;
    int wm = wid >> 1, wn = wid & 1;
    int lr = lane & 15, lq = lane >> 4;
    const bf16x8 zero8 = {0, 0, 0, 0, 0, 0, 0, 0};

    for (int k0 = 0; k0 < H_DIM; k0 += 32) {
        // A: 128x32 per plane, one 16B chunk per thread per plane, 2 iters
#pragma unroll
        for (int p = 0; p < 2; p++) {
            int c = tid + p * 256;
            int row = c >> 2, kh = (c & 3) * 8;
            int tok = toks[row];
            bf16x8 vh = zero8, vl = zero8;
            if (tok >= 0) {
                size_t g = (size_t)tok * H_DIM + k0 + kh;
                vh = *(const bf16x8*)&xh[g];
                vl = *(const bf16x8*)&xl[g];
            }
            int s = SWZ(row, kh);
            *(bf16x8*)&Ah[s] = vh;
            *(bf16x8*)&Al[s] = vl;
        }
        // B: 64x32, one chunk per thread per plane
        {
            int row = tid >> 2, kh = (tid & 3) * 8;
            size_t g = wbase + (size_t)(col0 + row) * H_DIM + k0 + kh;
            int s = SWZ(row, kh);
            *(bf16x8*)&B1h[s] = *(const bf16x8*)&w1h[g];
            *(bf16x8*)&B1l[s] = *(const bf16x8*)&w1l[g];
            *(bf16x8*)&B3h[s] = *(const bf16x8*)&w3h[g];
            *(bf16x8*)&B3l[s] = *(const bf16x8*)&w3l[g];
        }
        __syncthreads();

        bf16x8 ah[4], al[4];
#pragma unroll
        for (int i = 0; i < 4; i++) {
            int r = wm * 64 + i * 16 + lr;
            int s = SWZ(r, lq * 8);
            ah[i] = *(const bf16x8*)&Ah[s];
            al[i] = *(const bf16x8*)&Al[s];
        }
#pragma unroll
        for (int j = 0; j < 2; j++) {
            int rb = wn * 32 + j * 16 + lr;
            int s = SWZ(rb, lq * 8);
            bf16x8 b1h = *(const bf16x8*)&B1h[s];
            bf16x8 b1l = *(const bf16x8*)&B1l[s];
            bf16x8 b3h = *(const bf16x8*)&B3h[s];
            bf16x8 b3l = *(const bf16x8*)&B3l[s];
#pragma unroll
            for (int i = 0; i < 4; i++) {
                accu[i][j] = MFMA16(ah[i], b1h, accu[i][j]);
                accu[i][j] = MFMA16(ah[i], b1l, accu[i][j]);
                accu[i][j] = MFMA16(al[i], b1h, accu[i][j]);
                accv[i][j] = MFMA16(ah[i], b3h, accv[i][j]);
                accv[i][j] = MFMA16(ah[i], b3l, accv[i][j]);
                accv[i][j] = MFMA16(al[i], b3h, accv[i][j]);
            }
        }
        __syncthreads();
    }

#pragma unroll
    for (int i = 0; i < 4; i++) {
#pragma unroll
        for (int r = 0; r < 4; r++) {
            int lrow = wm * 64 + i * 16 + lq * 4 + r;
            int grow = row0 + lrow;
            if (grow < n_e) {
                size_t base = (size_t)(lbase + grow) * I_DIM + col0;
#pragma unroll
                for (int j = 0; j < 2; j++) {
                    float u = accu[i][j][r], v = accv[i][j][r];
                    float si = u / (1.f + expf(-u));
                    float val = si * v;
                    unsigned short h = f2bf(val);
                    unsigned short l = f2bf(val - bf2f(h));
                    int cidx = wn * 32 + j * 16 + lr;
                    hdnh[base + cidx] = h;
                    hdnl[base + cidx] = l;
                }
            }
        }
    }
}

// ---------------------------------------------------------------------------
// PS GEMM2: tile 128x128 over H, BK=32, 4 waves 2x2; atomic combine
// ---------------------------------------------------------------------------
__global__ __launch_bounds__(256) void gemm2_ps(
    const unsigned short* __restrict__ hdnh, const unsigned short* __restrict__ hdnl,
    const unsigned short* __restrict__ w2h, const unsigned short* __restrict__ w2l,
    const int* __restrict__ cnt, const int* __restrict__ offs,
    const int* __restrict__ idx_list, const float* __restrict__ wgt_list,
    float* __restrict__ out, int ebase)
{
    int z = blockIdx.z;
    int e = ebase + z;
    int n_e = cnt[e];
    int row0 = blockIdx.y * 128;
    if (row0 >= n_e) return;
    int col0 = blockIdx.x * 128;
    int lbase = offs[e];

    __shared__ unsigned short Ah[128 * 32], Al[128 * 32];
    __shared__ unsigned short Bh[128 * 32], Bl[128 * 32];
    __shared__ int   s_tok[128];
    __shared__ float s_wgt[128];

    int tid = threadIdx.x;
    if (tid < 128) {
        int r = row0 + tid;
        s_tok[tid] = (r < n_e) ? idx_list[lbase + r] : -1;
        s_wgt[tid] = (r < n_e) ? wgt_list[lbase + r] : 0.f;
    }

    const size_t wbase = (size_t)z * H_DIM * I_DIM;

    f32x4 acc[4][4];
#pragma unroll
    for (int i = 0; i < 4; i++)
#pragma unroll
        for (int j = 0; j < 4; j++) acc[i][j] = (f32x4)(0.f);

    int lane = tid & 63, wid = tid >> 6;
    int wm = wid >> 1, wn = wid & 1;
    int lr = lane & 15, lq = lane >> 4;
    const bf16x8 zero8 = {0, 0, 0, 0, 0, 0, 0, 0};

    for (int k0 = 0; k0 < I_DIM; k0 += 32) {
#pragma unroll
        for (int p = 0; p < 2; p++) {
            int c = tid + p * 256;
            int row = c >> 2, kh = (c & 3) * 8;
            bf16x8 vh = zero8, vl = zero8;
            if (row0 + row < n_e) {
                size_t g = (size_t)(lbase + row0 + row) * I_DIM + k0 + kh;
                vh = *(const bf16x8*)&hdnh[g];
                vl = *(const bf16x8*)&hdnl[g];
            }
            int s = SWZ(row, kh);
            *(bf16x8*)&Ah[s] = vh;
            *(bf16x8*)&Al[s] = vl;
        }
#pragma unroll
        for (int p = 0; p < 2; p++) {
            int c = tid + p * 256;
            int row = c >> 2, kh = (c & 3) * 8;
            size_t g = wbase + (size_t)(col0 + row) * I_DIM + k0 + kh;
            int s = SWZ(row, kh);
            *(bf16x8*)&Bh[s] = *(const bf16x8*)&w2h[g];
            *(bf16x8*)&Bl[s] = *(const bf16x8*)&w2l[g];
        }
        __syncthreads();

        bf16x8 ah[4], al[4];
#pragma unroll
        for (int i = 0; i < 4; i++) {
            int r = wm * 64 + i * 16 + lr;
            int s = SWZ(r, lq * 8);
            ah[i] = *(const bf16x8*)&Ah[s];
            al[i] = *(const bf16x8*)&Al[s];
        }
#pragma unroll
        for (int j = 0; j < 4; j++) {
            int rb = wn * 64 + j * 16 + lr;
            int s = SWZ(rb, lq * 8);
            bf16x8 bh = *(const bf16x8*)&Bh[s];
            bf16x8 bl = *(const bf16x8*)&Bl[s];
#pragma unroll
            for (int i = 0; i < 4; i++) {
                acc[i][j] = MFMA16(ah[i], bh, acc[i][j]);
                acc[i][j] = MFMA16(ah[i], bl, acc[i][j]);
                acc[i][j] = MFMA16(al[i], bh, acc[i][j]);
            }
        }
        __syncthreads();
    }

#pragma unroll
    for (int i = 0; i < 4; i++) {
#pragma unroll
        for (int r = 0; r < 4; r++) {
            int lrow = wm * 64 + i * 16 + lq * 4 + r;
            int grow = row0 + lrow;
            if (grow < n_e) {
                int t = s_tok[lrow];
                float wt = s_wgt[lrow];
                float* orow = out + (size_t)t * H_DIM + col0;
#pragma unroll
                for (int j = 0; j < 4; j++)
                    atomicAdd(&orow[wn * 64 + j * 16 + lr], wt * acc[i][j][r]);
            }
        }
    }
}

// ---------------------------------------------------------------------------
// Fallback (round-3 kernels: on-the-fly split, fp32 hdn)
// ---------------------------------------------------------------------------
__global__ __launch_bounds__(256) void gemm1_mfma(
    const float* __restrict__ xt, const float* __restrict__ w1,
    const float* __restrict__ w3,
    const int* __restrict__ cnt, const int* __restrict__ offs,
    const int* __restrict__ idx_list,
    float* __restrict__ hdn, int e_param, int compact)
{
    int e = (e_param >= 0) ? e_param : (int)blockIdx.z;
    int n_e = cnt[e];
    int row0 = blockIdx.y * 128;
    if (row0 >= n_e) return;
    int col0 = blockIdx.x * 64;
    int lbase = offs[e];
    size_t hbase = compact ? (size_t)lbase : 0;

    __shared__ unsigned short Ah[128 * 32], Al[128 * 32];
    __shared__ unsigned short B1h[64 * 32], B1l[64 * 32];
    __shared__ unsigned short B3h[64 * 32], B3l[64 * 32];
    __shared__ int toks[128];

    int tid = threadIdx.x;
    if (tid < 128) {
        int r = row0 + tid;
        toks[tid] = (r < n_e) ? idx_list[lbase + r] : -1;
    }
    __syncthreads();

    const float* w1e = w1 + (size_t)e * I_DIM * H_DIM;
    const float* w3e = w3 + (size_t)e * I_DIM * H_DIM;

    f32x4 accu[4][2], accv[4][2];
#pragma unroll
    for (int i = 0; i < 4; i++)
#pragma unroll
        for (int j = 0; j < 2; j++) { accu[i][j] = (f32x4)(0.f); accv[i][j] = (f32x4)(0.f); }

    int lane = tid & 63, wid = tid >> 6;
    int wm = wid >> 1, wn = wid & 1;
    int lr = lane & 15, lq = lane >> 4;

    for (int k0 = 0; k0 < H_DIM; k0 += 32) {
#pragma unroll
        for (int p = 0; p < 4; p++) {
            int idx = tid + p * 256;
            int row = idx >> 3, kq = (idx & 7) << 2;
            int tok = toks[row];
            float4 v = (tok >= 0)
                ? *(const float4*)&xt[(size_t)tok * H_DIM + k0 + kq]
                : make_float4(0.f, 0.f, 0.f, 0.f);
            unsigned hi[2], lo[2];
            split4(v, hi, lo);
            int s = SWZ(row, kq);
            *(uint2*)&Ah[s] = make_uint2(hi[0], hi[1]);
            *(uint2*)&Al[s] = make_uint2(lo[0], lo[1]);
        }
#pragma unroll
        for (int p = 0; p < 2; p++) {
            int idx = tid + p * 256;
            int row = idx >> 3, kq = (idx & 7) << 2;
            size_t goff = (size_t)(col0 + row) * H_DIM + k0 + kq;
            float4 v1 = *(const float4*)&w1e[goff];
            float4 v3 = *(const float4*)&w3e[goff];
            unsigned hi[2], lo[2];
            int s = SWZ(row, kq);
            split4(v1, hi, lo);
            *(uint2*)&B1h[s] = make_uint2(hi[0], hi[1]);
            *(uint2*)&B1l[s] = make_uint2(lo[0], lo[1]);
            split4(v3, hi, lo);
            *(uint2*)&B3h[s] = make_uint2(hi[0], hi[1]);
            *(uint2*)&B3l[s] = make_uint2(lo[0], lo[1]);
        }
        __syncthreads();

        bf16x8 ah[4], al[4];
#pragma unroll
        for (int i = 0; i < 4; i++) {
            int r = wm * 64 + i * 16 + lr;
            int s = SWZ(r, lq * 8);
            ah[i] = *(const bf16x8*)&Ah[s];
            al[i] = *(const bf16x8*)&Al[s];
        }
#pragma unroll
        for (int j = 0; j < 2; j++) {
            int rb = wn * 32 + j * 16 + lr;
            int s = SWZ(rb, lq * 8);
            bf16x8 b1h = *(const bf16x8*)&B1h[s];
            bf16x8 b1l = *(const bf16x8*)&B1l[s];
            bf16x8 b3h = *(const bf16x8*)&B3h[s];
            bf16x8 b3l = *(const bf16x8*)&B3l[s];
#pragma unroll
            for (int i = 0; i < 4; i++) {
                accu[i][j] = MFMA16(ah[i], b1h, accu[i][j]);
                accu[i][j] = MFMA16(ah[i], b1l, accu[i][j]);
                accu[i][j] = MFMA16(al[i], b1h, accu[i][j]);
                accv[i][j] = MFMA16(ah[i], b3h, accv[i][j]);
                accv[i][j] = MFMA16(ah[i], b3l, accv[i][j]);
                accv[i][j] = MFMA16(al[i], b3h, accv[i][j]);
            }
        }
        __syncthreads();
    }

#pragma unroll
    for (int i = 0; i < 4; i++) {
#pragma unroll
        for (int r = 0; r < 4; r++) {
            int lrow = wm * 64 + i * 16 + lq * 4 + r;
            int grow = row0 + lrow;
            if (grow < n_e) {
                float* hrow = hdn + (hbase + grow) * (size_t)I_DIM + col0;
#pragma unroll
                for (int j = 0; j < 2; j++) {
                    float u = accu[i][j][r];
                    float v = accv[i][j][r];
                    float si = u / (1.f + expf(-u));
                    hrow[wn * 32 + j * 16 + lr] = si * v;
                }
            }
        }
    }
}

__global__ __launch_bounds__(256) void gemm2_mfma(
    const float* __restrict__ hdn, const float* __restrict__ w2,
    const int* __restrict__ cnt, const int* __restrict__ offs,
    const int* __restrict__ idx_list, const float* __restrict__ wgt_list,
    float* __restrict__ out, int e_param, int compact)
{
    int e = (e_param >= 0) ? e_param : (int)blockIdx.z;
    int n_e = cnt[e];
    int row0 = blockIdx.y * 128;
    if (row0 >= n_e) return;
    int col0 = blockIdx.x * 128;
    int lbase = offs[e];
    size_t hbase = compact ? (size_t)lbase : 0;

    __shared__ unsigned short Ah[128 * 32], Al[128 * 32];
    __shared__ unsigned short Bh[128 * 32], Bl[128 * 32];
    __shared__ int   s_tok[128];
    __shared__ float s_wgt[128];

    int tid = threadIdx.x;
    if (tid < 128) {
        int r = row0 + tid;
        s_tok[tid] = (r < n_e) ? idx_list[lbase + r] : -1;
        s_wgt[tid] = (r < n_e) ? wgt_list[lbase + r] : 0.f;
    }

    const float* w2e = w2 + (size_t)e * H_DIM * I_DIM;

    f32x4 acc[4][4];
#pragma unroll
    for (int i = 0; i < 4; i++)
#pragma unroll
        for (int j = 0; j < 4; j++) acc[i][j] = (f32x4)(0.f);

    int lane = tid & 63, wid = tid >> 6;
    int wm = wid >> 1, wn = wid & 1;
    int lr = lane & 15, lq = lane >> 4;

    for (int k0 = 0; k0 < I_DIM; k0 += 32) {
#pragma unroll
        for (int p = 0; p < 4; p++) {
            int idx = tid + p * 256;
            int row = idx >> 3, kq = (idx & 7) << 2;
            float4 v = (row0 + row < n_e)
                ? *(const float4*)&hdn[(hbase + row0 + row) * (size_t)I_DIM + k0 + kq]
                : make_float4(0.f, 0.f, 0.f, 0.f);
            unsigned hi[2], lo[2];
            split4(v, hi, lo);
            int s = SWZ(row, kq);
            *(uint2*)&Ah[s] = make_uint2(hi[0], hi[1]);
            *(uint2*)&Al[s] = make_uint2(lo[0], lo[1]);
        }
#pragma unroll
        for (int p = 0; p < 4; p++) {
            int idx = tid + p * 256;
            int row = idx >> 3, kq = (idx & 7) << 2;
            float4 v = *(const float4*)&w2e[(size_t)(col0 + row) * I_DIM + k0 + kq];
            unsigned hi[2], lo[2];
            split4(v, hi, lo);
            int s = SWZ(row, kq);
            *(uint2*)&Bh[s] = make_uint2(hi[0], hi[1]);
            *(uint2*)&Bl[s] = make_uint2(lo[0], lo[1]);
        }
        __syncthreads();

        bf16x8 ah[4], al[4];
#pragma unroll
        for (int i = 0; i < 4; i++) {
            int r = wm * 64 + i * 16 + lr;
            int s = SWZ(r, lq * 8);
            ah[i] = *(const bf16x8*)&Ah[s];
            al[i] = *(const bf16x8*)&Al[s];
        }
#pragma unroll
        for (int j = 0; j < 4; j++) {
            int rb = wn * 64 + j * 16 + lr;
            int s = SWZ(rb, lq * 8);
            bf16x8 bh = *(const bf16x8*)&Bh[s];
            bf16x8 bl = *(const bf16x8*)&Bl[s];
#pragma unroll
            for (int i = 0; i < 4; i++) {
                acc[i][j] = MFMA16(ah[i], bh, acc[i][j]);
                acc[i][j] = MFMA16(ah[i], bl, acc[i][j]);
                acc[i][j] = MFMA16(al[i], bh, acc[i][j]);
            }
        }
        __syncthreads();
    }

#pragma unroll
    for (int i = 0; i < 4; i++) {
#pragma unroll
        for (int r = 0; r < 4; r++) {
            int lrow = wm * 64 + i * 16 + lq * 4 + r;
            int grow = row0 + lrow;
            if (grow < n_e) {
                int t = s_tok[lrow];
                float wt = s_wgt[lrow];
                float* orow = out + (size_t)t * H_DIM + col0;
#pragma unroll
                for (int j = 0; j < 4; j++)
                    atomicAdd(&orow[wn * 64 + j * 16 + lr], wt * acc[i][j][r]);
            }
        }
    }
}

extern "C" void kernel_launch(void* const* d_in, const int* in_sizes, int n_in,
                              void* d_out, int out_size, void* d_ws, size_t ws_size,
                              hipStream_t stream) {
    const float* x  = (const float*)d_in[0];
    const float* gw = (const float*)d_in[1];
    const float* w1 = (const float*)d_in[2];
    const float* w2 = (const float*)d_in[3];
    const float* w3 = (const float*)d_in[4];
    float* out = (float*)d_out;

    char* ws = (char*)d_ws;
    int*   cnt      = (int*)(ws + 0);
    int*   cursor   = (int*)(ws + 32);
    float* probsum  = (float*)(ws + 64);
    int*   offs     = (int*)(ws + 96);
    int*   tok_e    = (int*)(ws + 256);
    float* tok_w    = (float*)(ws + 256 + 65536);
    int*   idx_list = (int*)(ws + 256 + 2 * 65536);
    float* wgt_list = (float*)(ws + 256 + 3 * 65536);
    size_t buf0     = 256 + 4 * 65536;     // 262400, 256-aligned

    const size_t XP = (size_t)T_TOK * H_DIM * 2;     // x plane: 16.78 MB
    const size_t WP = (size_t)I_DIM * H_DIM * 2;     // weight plane/expert: 4.19 MB
    const size_t DP = (size_t)T_TOK * K_TOP * I_DIM * 2;  // hdn plane: 67.1 MB

    // choose largest expert-group size EG whose layout fits
    int EG = 0;
    size_t xh_o = 0, xl_o = 0, wslot_o = 0, dh_o = 0, dl_o = 0;
    for (int eg = E_EXP; eg >= 1; eg >>= 1) {
        size_t off = buf0;
        size_t a = off; off += XP;           // xh
        size_t b = off; off += XP;           // xl
        size_t c = off; off += 4 * eg * WP;  // wslot (w1h,w1l,w3h,w3l | aliased by w2h,w2l)
        size_t d = off; off += DP;           // hdnh
        size_t f = off; off += DP;           // hdnl
        if (off <= ws_size) { EG = eg; xh_o = a; xl_o = b; wslot_o = c; dh_o = d; dl_o = f; break; }
    }
    size_t need1 = buf0 + (size_t)T_TOK * K_TOP * I_DIM * sizeof(float);

    hipMemsetAsync(ws, 0, 128, stream);
    hipMemsetAsync(d_out, 0, (size_t)T_TOK * H_DIM * sizeof(float), stream);

    gate_kernel<<<T_TOK / 4, 256, 0, stream>>>(x, gw, cnt, probsum, tok_e, tok_w);
    offs_aux_kernel<<<1, 64, 0, stream>>>(cnt, probsum, offs, cursor,
                                          out + (size_t)T_TOK * H_DIM);
    scatter_kernel<<<T_TOK / 256, 256, 0, stream>>>(tok_e, tok_w, cursor,
                                                    idx_list, wgt_list);

    if (EG >= 1) {
        unsigned short* xh = (unsigned short*)(ws + xh_o);
        unsigned short* xl = (unsigned short*)(ws + xl_o);
        unsigned short* dh = (unsigned short*)(ws + dh_o);
        unsigned short* dl = (unsigned short*)(ws + dl_o);
        // wslot layout (per group): [w1h | w1l | w3h | w3l], each EG*WP bytes.
        // w2 phase aliases the first 2*EG*WP bytes as [w2h | w2l].
        unsigned short* s_w1h = (unsigned short*)(ws + wslot_o + 0 * EG * WP);
        unsigned short* s_w1l = (unsigned short*)(ws + wslot_o + 1 * EG * WP);
        unsigned short* s_w3h = (unsigned short*)(ws + wslot_o + 2 * EG * WP);
        unsigned short* s_w3l = (unsigned short*)(ws + wslot_o + 3 * EG * WP);
        unsigned short* s_w2h = (unsigned short*)(ws + wslot_o + 0 * EG * WP);
        unsigned short* s_w2l = (unsigned short*)(ws + wslot_o + 1 * EG * WP);

        {   // pre-split x once
            int nch = T_TOK * H_DIM / 8;
            int g = (nch + 255) / 256; if (g > 2048) g = 2048;
            convert_split_kernel<<<g, 256, 0, stream>>>(
                (const float4*)x, (uint4*)xh, (uint4*)xl, nch);
        }
        const int wch = (int)((size_t)EG * I_DIM * H_DIM / 8);
        int wg = (wch + 255) / 256; if (wg > 2048) wg = 2048;

        for (int eb = 0; eb < E_EXP; eb += EG) {
            const size_t woff = (size_t)eb * I_DIM * H_DIM;
            convert_split_kernel<<<wg, 256, 0, stream>>>(
                (const float4*)(w1 + woff), (uint4*)s_w1h, (uint4*)s_w1l, wch);
            convert_split_kernel<<<wg, 256, 0, stream>>>(
                (const float4*)(w3 + woff), (uint4*)s_w3h, (uint4*)s_w3l, wch);
            dim3 g1(I_DIM / 64, T_TOK / 128, EG);
            gemm1_ps<<<g1, 256, 0, stream>>>(xh, xl, s_w1h, s_w1l, s_w3h, s_w3l,
                                             cnt, offs, idx_list, dh, dl, eb);
            convert_split_kernel<<<wg, 256, 0, stream>>>(
                (const float4*)(w2 + woff), (uint4*)s_w2h, (uint4*)s_w2l, wch);
            dim3 g2(H_DIM / 128, T_TOK / 128, EG);
            gemm2_ps<<<g2, 256, 0, stream>>>(dh, dl, s_w2h, s_w2l,
                                             cnt, offs, idx_list, wgt_list, out, eb);
        }
    } else if (ws_size >= need1) {
        float* hdn = (float*)(ws + buf0);
        dim3 g1(I_DIM / 64, T_TOK / 128, E_EXP);
        gemm1_mfma<<<g1, 256, 0, stream>>>(x, w1, w3, cnt, offs, idx_list, hdn, -1, 1);
        dim3 g2(H_DIM / 128, T_TOK / 128, E_EXP);
        gemm2_mfma<<<g2, 256, 0, stream>>>(hdn, w2, cnt, offs, idx_list, wgt_list,
                                           out, -1, 1);
    } else {
        float* hdn = (float*)(ws + buf0);
        for (int e = 0; e < E_EXP; e++) {
            gemm1_mfma<<<dim3(I_DIM / 64, T_TOK / 128, 1), 256, 0, stream>>>(
                x, w1, w3, cnt, offs, idx_list, hdn, e, 0);
            gemm2_mfma<<<dim3(H_DIM / 128, T_TOK / 128, 1), 256, 0, stream>>>(
                hdn, w2, cnt, offs, idx_list, wgt_list, out, e, 0);
        }
    }
}

// Round 6
// 1127.810 us; speedup vs baseline: 3.1838x; 1.4267x over previous
//
#include <hip/hip_runtime.h>
#include <hip/hip_bf16.h>
#include <math.h>

#define T_TOK 8192
#define H_DIM 1024
#define E_EXP 8
#define K_TOP 2
#define I_DIM 2048

typedef short bf16x8 __attribute__((ext_vector_type(8)));
typedef float f32x4 __attribute__((ext_vector_type(4)));

#define MFMA16(a, b, c) __builtin_amdgcn_mfma_f32_16x16x32_bf16((a), (b), (c), 0, 0, 0)

// LDS swizzle (units = shorts, row stride 32 shorts = 64B):
// XOR 16B-slot index with (row&7); bijective, applied on write AND read.
#define SWZ(r, k) ((((r) * 32) + (k)) ^ (((r) & 7) << 3))

__device__ __forceinline__ unsigned short f2bf(float f) {
    unsigned u = __builtin_bit_cast(unsigned, f);
    u += 0x7fffu + ((u >> 16) & 1u);          // RNE
    return (unsigned short)(u >> 16);
}
__device__ __forceinline__ float bf2f(unsigned short s) {
    return __builtin_bit_cast(float, ((unsigned)s) << 16);
}
__device__ __forceinline__ void split4(float4 v, unsigned* hi, unsigned* lo) {
    unsigned short hx = f2bf(v.x), hy = f2bf(v.y), hz = f2bf(v.z), hw = f2bf(v.w);
    unsigned short lx = f2bf(v.x - bf2f(hx)), ly = f2bf(v.y - bf2f(hy));
    unsigned short lz = f2bf(v.z - bf2f(hz)), lw = f2bf(v.w - bf2f(hw));
    hi[0] = (unsigned)hx | ((unsigned)hy << 16);
    hi[1] = (unsigned)hz | ((unsigned)hw << 16);
    lo[0] = (unsigned)lx | ((unsigned)ly << 16);
    lo[1] = (unsigned)lz | ((unsigned)lw << 16);
}

// ---------------------------------------------------------------------------
// Workspace (bytes):
//   0: cnt[8] | 32: cursor[8] | 64: probsum[8] | 96: offs[8]
//   256: tok_e | +64K: tok_w | +64K: idx_list | +64K: wgt_list
//   buf0 (262400):
//     PS tier: xh,xl (33.5MB) | wslot (4*EG*4.19MB, w2 aliases) | hdnh,hdnl (134.2MB)
//     fallback tier: hdn fp32 compact (134.2MB)
// ---------------------------------------------------------------------------

__global__ __launch_bounds__(256) void gate_kernel(
    const float* __restrict__ xt, const float* __restrict__ gw,
    int* __restrict__ cnt, float* __restrict__ probsum,
    int* __restrict__ tok_e, float* __restrict__ tok_w)
{
    __shared__ float s_probs[4][8];
    __shared__ int   s_cnt[8];
    int tid = threadIdx.x;
    if (tid < 8) s_cnt[tid] = 0;
    __syncthreads();

    int wave = tid >> 6, lane = tid & 63;
    int t = blockIdx.x * 4 + wave;

    float acc[8];
#pragma unroll
    for (int e = 0; e < 8; e++) acc[e] = 0.f;
    const float* xrow = xt + (size_t)t * H_DIM;
    for (int k = lane; k < H_DIM; k += 64) {
        float xv = xrow[k];
#pragma unroll
        for (int e = 0; e < 8; e++) acc[e] = fmaf(xv, gw[e * H_DIM + k], acc[e]);
    }
#pragma unroll
    for (int off = 32; off > 0; off >>= 1) {
#pragma unroll
        for (int e = 0; e < 8; e++) acc[e] += __shfl_down(acc[e], off);
    }
    if (lane == 0) {
        float mx = acc[0];
#pragma unroll
        for (int e = 1; e < 8; e++) mx = fmaxf(mx, acc[e]);
        float p[8]; float sum = 0.f;
#pragma unroll
        for (int e = 0; e < 8; e++) { p[e] = expf(acc[e] - mx); sum += p[e]; }
        float inv = 1.f / sum;
#pragma unroll
        for (int e = 0; e < 8; e++) p[e] *= inv;
        int i0 = 0;
#pragma unroll
        for (int e = 1; e < 8; e++) if (p[e] > p[i0]) i0 = e;
        int i1 = (i0 == 0) ? 1 : 0;
#pragma unroll
        for (int e = 0; e < 8; e++) if (e != i0 && p[e] > p[i1]) i1 = e;
        float w0 = p[i0], w1v = p[i1];
        float denom = w0 + w1v + 1e-6f;
        tok_e[t * 2 + 0] = i0;            tok_e[t * 2 + 1] = i1;
        tok_w[t * 2 + 0] = w0 / denom;    tok_w[t * 2 + 1] = w1v / denom;
        atomicAdd(&s_cnt[i0], 1);
        atomicAdd(&s_cnt[i1], 1);
#pragma unroll
        for (int e = 0; e < 8; e++) s_probs[wave][e] = p[e];
    }
    __syncthreads();
    if (tid < 8) {
        float s = s_probs[0][tid] + s_probs[1][tid] + s_probs[2][tid] + s_probs[3][tid];
        atomicAdd(&probsum[tid], s);
        if (s_cnt[tid]) atomicAdd(&cnt[tid], s_cnt[tid]);
    }
}

__global__ void offs_aux_kernel(const int* __restrict__ cnt,
                                const float* __restrict__ probsum,
                                int* __restrict__ offs, int* __restrict__ cursor,
                                float* __restrict__ out_aux)
{
    if (threadIdx.x == 0 && blockIdx.x == 0) {
        int o = 0; float aux = 0.f;
        for (int e = 0; e < E_EXP; e++) {
            offs[e] = o; cursor[e] = o; o += cnt[e];
            aux += (float)cnt[e] * probsum[e];
        }
        out_aux[0] = aux * (float)E_EXP / ((float)T_TOK * (float)T_TOK);
    }
}

__global__ __launch_bounds__(256) void scatter_kernel(
    const int* __restrict__ tok_e, const float* __restrict__ tok_w,
    int* __restrict__ cursor, int* __restrict__ idx_list, float* __restrict__ wgt_list)
{
    int t = blockIdx.x * 256 + threadIdx.x;
#pragma unroll
    for (int s = 0; s < K_TOP; s++) {
        int e = tok_e[t * 2 + s];
        int pos = atomicAdd(&cursor[e], 1);
        idx_list[pos] = t;
        wgt_list[pos] = tok_w[t * 2 + s];
    }
}

// fp32 -> (bf16 hi plane, bf16 lo plane), 8 elems/iter
__global__ __launch_bounds__(256) void convert_split_kernel(
    const float4* __restrict__ src, uint4* __restrict__ hi, uint4* __restrict__ lo,
    int nchunk)
{
    int stride = gridDim.x * blockDim.x;
    for (int c = blockIdx.x * blockDim.x + threadIdx.x; c < nchunk; c += stride) {
        float4 a = src[2 * c + 0];
        float4 b = src[2 * c + 1];
        unsigned h[4], l[4];
        split4(a, &h[0], &l[0]);
        split4(b, &h[2], &l[2]);
        hi[c] = make_uint4(h[0], h[1], h[2], h[3]);
        lo[c] = make_uint4(l[0], l[1], l[2], l[3]);
    }
}

// ---------------------------------------------------------------------------
// PS GEMM1 (2-phase): dbuf LDS + register prefetch, 1 barrier/K-step.
// tile 128x64, BK=32, 4 waves 2x2. e = ebase + blockIdx.z (slot-relative W).
// ---------------------------------------------------------------------------
__global__ __launch_bounds__(256) void gemm1_ps(
    const unsigned short* __restrict__ xh, const unsigned short* __restrict__ xl,
    const unsigned short* __restrict__ w1h, const unsigned short* __restrict__ w1l,
    const unsigned short* __restrict__ w3h, const unsigned short* __restrict__ w3l,
    const int* __restrict__ cnt, const int* __restrict__ offs,
    const int* __restrict__ idx_list,
    unsigned short* __restrict__ hdnh, unsigned short* __restrict__ hdnl, int ebase)
{
    int z = blockIdx.z;
    int e = ebase + z;
    int n_e = cnt[e];
    int row0 = blockIdx.y * 128;
    if (row0 >= n_e) return;
    int col0 = blockIdx.x * 64;
    int lbase = offs[e];

    __shared__ unsigned short Ah[2][128 * 32], Al[2][128 * 32];
    __shared__ unsigned short B1h[2][64 * 32], B1l[2][64 * 32];
    __shared__ unsigned short B3h[2][64 * 32], B3l[2][64 * 32];
    __shared__ int toks[128];

    int tid = threadIdx.x;
    if (tid < 128) {
        int r = row0 + tid;
        toks[tid] = (r < n_e) ? idx_list[lbase + r] : -1;
    }
    __syncthreads();

    const size_t wbase = (size_t)z * I_DIM * H_DIM;
    const bf16x8 zero8 = {0, 0, 0, 0, 0, 0, 0, 0};

    // staging ownership
    int arow0 = tid >> 2,  akh = (tid & 3) * 8;   // A pos p: row arow0 + p*64
    int brow  = tid >> 2,  bkh = (tid & 3) * 8;   // B row 0..63
    int tokA0 = toks[arow0], tokA1 = toks[arow0 + 64];
    size_t bgoff = wbase + (size_t)(col0 + brow) * H_DIM + bkh;

    // prefetch regs
    bf16x8 pAh0, pAl0, pAh1, pAl1, pB1h, pB1l, pB3h, pB3l;

#define G1_LOAD(K0)                                                            \
    {                                                                          \
        if (tokA0 >= 0) {                                                      \
            size_t g = (size_t)tokA0 * H_DIM + (K0) + akh;                     \
            pAh0 = *(const bf16x8*)&xh[g]; pAl0 = *(const bf16x8*)&xl[g];      \
        } else { pAh0 = zero8; pAl0 = zero8; }                                 \
        if (tokA1 >= 0) {                                                      \
            size_t g = (size_t)tokA1 * H_DIM + (K0) + akh;                     \
            pAh1 = *(const bf16x8*)&xh[g]; pAl1 = *(const bf16x8*)&xl[g];      \
        } else { pAh1 = zero8; pAl1 = zero8; }                                 \
        size_t gb = bgoff + (K0);                                              \
        pB1h = *(const bf16x8*)&w1h[gb]; pB1l = *(const bf16x8*)&w1l[gb];      \
        pB3h = *(const bf16x8*)&w3h[gb]; pB3l = *(const bf16x8*)&w3l[gb];      \
    }

#define G1_WRITE(BUF)                                                          \
    {                                                                          \
        int s0 = SWZ(arow0, akh);                                              \
        *(bf16x8*)&Ah[BUF][s0] = pAh0; *(bf16x8*)&Al[BUF][s0] = pAl0;          \
        int s1 = SWZ(arow0 + 64, akh);                                         \
        *(bf16x8*)&Ah[BUF][s1] = pAh1; *(bf16x8*)&Al[BUF][s1] = pAl1;          \
        int sb = SWZ(brow, bkh);                                               \
        *(bf16x8*)&B1h[BUF][sb] = pB1h; *(bf16x8*)&B1l[BUF][sb] = pB1l;        \
        *(bf16x8*)&B3h[BUF][sb] = pB3h; *(bf16x8*)&B3l[BUF][sb] = pB3l;        \
    }

    f32x4 accu[4][2], accv[4][2];
#pragma unroll
    for (int i = 0; i < 4; i++)
#pragma unroll
        for (int j = 0; j < 2; j++) { accu[i][j] = (f32x4)(0.f); accv[i][j] = (f32x4)(0.f); }

    int lane = tid & 63, wid = tid >> 6;
    int wm = wid >> 1, wn = wid & 1;
    int lr = lane & 15, lq = lane >> 4;

    const int NT = H_DIM / 32;
    G1_LOAD(0);
    G1_WRITE(0);
    __syncthreads();

    for (int t = 0; t < NT; ++t) {
        int cur = t & 1;
        if (t + 1 < NT) G1_LOAD((t + 1) * 32);

        bf16x8 ah[4], al[4];
#pragma unroll
        for (int i = 0; i < 4; i++) {
            int r = wm * 64 + i * 16 + lr;
            int s = SWZ(r, lq * 8);
            ah[i] = *(const bf16x8*)&Ah[cur][s];
            al[i] = *(const bf16x8*)&Al[cur][s];
        }
#pragma unroll
        for (int j = 0; j < 2; j++) {
            int rb = wn * 32 + j * 16 + lr;
            int s = SWZ(rb, lq * 8);
            bf16x8 b1h = *(const bf16x8*)&B1h[cur][s];
            bf16x8 b1l = *(const bf16x8*)&B1l[cur][s];
            bf16x8 b3h = *(const bf16x8*)&B3h[cur][s];
            bf16x8 b3l = *(const bf16x8*)&B3l[cur][s];
#pragma unroll
            for (int i = 0; i < 4; i++) {
                accu[i][j] = MFMA16(ah[i], b1h, accu[i][j]);
                accu[i][j] = MFMA16(ah[i], b1l, accu[i][j]);
                accu[i][j] = MFMA16(al[i], b1h, accu[i][j]);
                accv[i][j] = MFMA16(ah[i], b3h, accv[i][j]);
                accv[i][j] = MFMA16(ah[i], b3l, accv[i][j]);
                accv[i][j] = MFMA16(al[i], b3h, accv[i][j]);
            }
        }
        if (t + 1 < NT) G1_WRITE((t + 1) & 1);
        __syncthreads();
    }
#undef G1_LOAD
#undef G1_WRITE

#pragma unroll
    for (int i = 0; i < 4; i++) {
#pragma unroll
        for (int r = 0; r < 4; r++) {
            int lrow = wm * 64 + i * 16 + lq * 4 + r;
            int grow = row0 + lrow;
            if (grow < n_e) {
                size_t base = (size_t)(lbase + grow) * I_DIM + col0;
#pragma unroll
                for (int j = 0; j < 2; j++) {
                    float u = accu[i][j][r], v = accv[i][j][r];
                    float si = u / (1.f + expf(-u));
                    float val = si * v;
                    unsigned short h = f2bf(val);
                    unsigned short l = f2bf(val - bf2f(h));
                    int cidx = wn * 32 + j * 16 + lr;
                    hdnh[base + cidx] = h;
                    hdnl[base + cidx] = l;
                }
            }
        }
    }
}

// ---------------------------------------------------------------------------
// PS GEMM2 (2-phase): tile 128x128 over H, BK=32, 4 waves 2x2; atomic combine
// ---------------------------------------------------------------------------
__global__ __launch_bounds__(256) void gemm2_ps(
    const unsigned short* __restrict__ hdnh, const unsigned short* __restrict__ hdnl,
    const unsigned short* __restrict__ w2h, const unsigned short* __restrict__ w2l,
    const int* __restrict__ cnt, const int* __restrict__ offs,
    const int* __restrict__ idx_list, const float* __restrict__ wgt_list,
    float* __restrict__ out, int ebase)
{
    int z = blockIdx.z;
    int e = ebase + z;
    int n_e = cnt[e];
    int row0 = blockIdx.y * 128;
    if (row0 >= n_e) return;
    int col0 = blockIdx.x * 128;
    int lbase = offs[e];

    __shared__ unsigned short Ah[2][128 * 32], Al[2][128 * 32];
    __shared__ unsigned short Bh[2][128 * 32], Bl[2][128 * 32];
    __shared__ int   s_tok[128];
    __shared__ float s_wgt[128];

    int tid = threadIdx.x;
    if (tid < 128) {
        int r = row0 + tid;
        s_tok[tid] = (r < n_e) ? idx_list[lbase + r] : -1;
        s_wgt[tid] = (r < n_e) ? wgt_list[lbase + r] : 0.f;
    }

    const size_t wbase = (size_t)z * H_DIM * I_DIM;
    const bf16x8 zero8 = {0, 0, 0, 0, 0, 0, 0, 0};

    int arow0 = tid >> 2, akh = (tid & 3) * 8;        // A rows arow0, arow0+64
    int g0ok = (row0 + arow0 < n_e), g1ok = (row0 + arow0 + 64 < n_e);
    size_t ag0 = (size_t)(lbase + row0 + arow0) * I_DIM + akh;
    size_t ag1 = (size_t)(lbase + row0 + arow0 + 64) * I_DIM + akh;
    size_t bg0 = wbase + (size_t)(col0 + arow0) * I_DIM + akh;
    size_t bg1 = wbase + (size_t)(col0 + arow0 + 64) * I_DIM + akh;

    bf16x8 pAh0, pAl0, pAh1, pAl1, pBh0, pBl0, pBh1, pBl1;

#define G2_LOAD(K0)                                                            \
    {                                                                          \
        if (g0ok) { pAh0 = *(const bf16x8*)&hdnh[ag0 + (K0)];                  \
                    pAl0 = *(const bf16x8*)&hdnl[ag0 + (K0)]; }                \
        else { pAh0 = zero8; pAl0 = zero8; }                                   \
        if (g1ok) { pAh1 = *(const bf16x8*)&hdnh[ag1 + (K0)];                  \
                    pAl1 = *(const bf16x8*)&hdnl[ag1 + (K0)]; }                \
        else { pAh1 = zero8; pAl1 = zero8; }                                   \
        pBh0 = *(const bf16x8*)&w2h[bg0 + (K0)];                               \
        pBl0 = *(const bf16x8*)&w2l[bg0 + (K0)];                               \
        pBh1 = *(const bf16x8*)&w2h[bg1 + (K0)];                               \
        pBl1 = *(const bf16x8*)&w2l[bg1 + (K0)];                               \
    }

#define G2_WRITE(BUF)                                                          \
    {                                                                          \
        int s0 = SWZ(arow0, akh);                                              \
        *(bf16x8*)&Ah[BUF][s0] = pAh0; *(bf16x8*)&Al[BUF][s0] = pAl0;          \
        *(bf16x8*)&Bh[BUF][s0] = pBh0; *(bf16x8*)&Bl[BUF][s0] = pBl0;          \
        int s1 = SWZ(arow0 + 64, akh);                                         \
        *(bf16x8*)&Ah[BUF][s1] = pAh1; *(bf16x8*)&Al[BUF][s1] = pAl1;          \
        *(bf16x8*)&Bh[BUF][s1] = pBh1; *(bf16x8*)&Bl[BUF][s1] = pBl1;          \
    }

    f32x4 acc[4][4];
#pragma unroll
    for (int i = 0; i < 4; i++)
#pragma unroll
        for (int j = 0; j < 4; j++) acc[i][j] = (f32x4)(0.f);

    int lane = tid & 63, wid = tid >> 6;
    int wm = wid >> 1, wn = wid & 1;
    int lr = lane & 15, lq = lane >> 4;

    const int NT = I_DIM / 32;
    G2_LOAD(0);
    G2_WRITE(0);
    __syncthreads();

    for (int t = 0; t < NT; ++t) {
        int cur = t & 1;
        if (t + 1 < NT) G2_LOAD((t + 1) * 32);

        bf16x8 ah[4], al[4];
#pragma unroll
        for (int i = 0; i < 4; i++) {
            int r = wm * 64 + i * 16 + lr;
            int s = SWZ(r, lq * 8);
            ah[i] = *(const bf16x8*)&Ah[cur][s];
            al[i] = *(const bf16x8*)&Al[cur][s];
        }
#pragma unroll
        for (int j = 0; j < 4; j++) {
            int rb = wn * 64 + j * 16 + lr;
            int s = SWZ(rb, lq * 8);
            bf16x8 bh = *(const bf16x8*)&Bh[cur][s];
            bf16x8 bl = *(const bf16x8*)&Bl[cur][s];
#pragma unroll
            for (int i = 0; i < 4; i++) {
                acc[i][j] = MFMA16(ah[i], bh, acc[i][j]);
                acc[i][j] = MFMA16(ah[i], bl, acc[i][j]);
                acc[i][j] = MFMA16(al[i], bh, acc[i][j]);
            }
        }
        if (t + 1 < NT) G2_WRITE((t + 1) & 1);
        __syncthreads();
    }
#undef G2_LOAD
#undef G2_WRITE

#pragma unroll
    for (int i = 0; i < 4; i++) {
#pragma unroll
        for (int r = 0; r < 4; r++) {
            int lrow = wm * 64 + i * 16 + lq * 4 + r;
            int grow = row0 + lrow;
            if (grow < n_e) {
                int t = s_tok[lrow];
                float wt = s_wgt[lrow];
                float* orow = out + (size_t)t * H_DIM + col0;
#pragma unroll
                for (int j = 0; j < 4; j++)
                    atomicAdd(&orow[wn * 64 + j * 16 + lr], wt * acc[i][j][r]);
            }
        }
    }
}

// ---------------------------------------------------------------------------
// Fallback (single-buffer, on-the-fly split, fp32 hdn) — used only if ws tiny
// ---------------------------------------------------------------------------
__global__ __launch_bounds__(256) void gemm1_mfma(
    const float* __restrict__ xt, const float* __restrict__ w1,
    const float* __restrict__ w3,
    const int* __restrict__ cnt, const int* __restrict__ offs,
    const int* __restrict__ idx_list,
    float* __restrict__ hdn, int e_param, int compact)
{
    int e = (e_param >= 0) ? e_param : (int)blockIdx.z;
    int n_e = cnt[e];
    int row0 = blockIdx.y * 128;
    if (row0 >= n_e) return;
    int col0 = blockIdx.x * 64;
    int lbase = offs[e];
    size_t hbase = compact ? (size_t)lbase : 0;

    __shared__ unsigned short Ah[128 * 32], Al[128 * 32];
    __shared__ unsigned short B1h[64 * 32], B1l[64 * 32];
    __shared__ unsigned short B3h[64 * 32], B3l[64 * 32];
    __shared__ int toks[128];

    int tid = threadIdx.x;
    if (tid < 128) {
        int r = row0 + tid;
        toks[tid] = (r < n_e) ? idx_list[lbase + r] : -1;
    }
    __syncthreads();

    const float* w1e = w1 + (size_t)e * I_DIM * H_DIM;
    const float* w3e = w3 + (size_t)e * I_DIM * H_DIM;

    f32x4 accu[4][2], accv[4][2];
#pragma unroll
    for (int i = 0; i < 4; i++)
#pragma unroll
        for (int j = 0; j < 2; j++) { accu[i][j] = (f32x4)(0.f); accv[i][j] = (f32x4)(0.f); }

    int lane = tid & 63, wid = tid >> 6;
    int wm = wid >> 1, wn = wid & 1;
    int lr = lane & 15, lq = lane >> 4;

    for (int k0 = 0; k0 < H_DIM; k0 += 32) {
#pragma unroll
        for (int p = 0; p < 4; p++) {
            int idx = tid + p * 256;
            int row = idx >> 3, kq = (idx & 7) << 2;
            int tok = toks[row];
            float4 v = (tok >= 0)
                ? *(const float4*)&xt[(size_t)tok * H_DIM + k0 + kq]
                : make_float4(0.f, 0.f, 0.f, 0.f);
            unsigned hi[2], lo[2];
            split4(v, hi, lo);
            int s = SWZ(row, kq);
            *(uint2*)&Ah[s] = make_uint2(hi[0], hi[1]);
            *(uint2*)&Al[s] = make_uint2(lo[0], lo[1]);
        }
#pragma unroll
        for (int p = 0; p < 2; p++) {
            int idx = tid + p * 256;
            int row = idx >> 3, kq = (idx & 7) << 2;
            size_t goff = (size_t)(col0 + row) * H_DIM + k0 + kq;
            float4 v1 = *(const float4*)&w1e[goff];
            float4 v3 = *(const float4*)&w3e[goff];
            unsigned hi[2], lo[2];
            int s = SWZ(row, kq);
            split4(v1, hi, lo);
            *(uint2*)&B1h[s] = make_uint2(hi[0], hi[1]);
            *(uint2*)&B1l[s] = make_uint2(lo[0], lo[1]);
            split4(v3, hi, lo);
            *(uint2*)&B3h[s] = make_uint2(hi[0], hi[1]);
            *(uint2*)&B3l[s] = make_uint2(lo[0], lo[1]);
        }
        __syncthreads();

        bf16x8 ah[4], al[4];
#pragma unroll
        for (int i = 0; i < 4; i++) {
            int r = wm * 64 + i * 16 + lr;
            int s = SWZ(r, lq * 8);
            ah[i] = *(const bf16x8*)&Ah[s];
            al[i] = *(const bf16x8*)&Al[s];
        }
#pragma unroll
        for (int j = 0; j < 2; j++) {
            int rb = wn * 32 + j * 16 + lr;
            int s = SWZ(rb, lq * 8);
            bf16x8 b1h = *(const bf16x8*)&B1h[s];
            bf16x8 b1l = *(const bf16x8*)&B1l[s];
            bf16x8 b3h = *(const bf16x8*)&B3h[s];
            bf16x8 b3l = *(const bf16x8*)&B3l[s];
#pragma unroll
            for (int i = 0; i < 4; i++) {
                accu[i][j] = MFMA16(ah[i], b1h, accu[i][j]);
                accu[i][j] = MFMA16(ah[i], b1l, accu[i][j]);
                accu[i][j] = MFMA16(al[i], b1h, accu[i][j]);
                accv[i][j] = MFMA16(ah[i], b3h, accv[i][j]);
                accv[i][j] = MFMA16(ah[i], b3l, accv[i][j]);
                accv[i][j] = MFMA16(al[i], b3h, accv[i][j]);
            }
        }
        __syncthreads();
    }

#pragma unroll
    for (int i = 0; i < 4; i++) {
#pragma unroll
        for (int r = 0; r < 4; r++) {
            int lrow = wm * 64 + i * 16 + lq * 4 + r;
            int grow = row0 + lrow;
            if (grow < n_e) {
                float* hrow = hdn + (hbase + grow) * (size_t)I_DIM + col0;
#pragma unroll
                for (int j = 0; j < 2; j++) {
                    float u = accu[i][j][r];
                    float v = accv[i][j][r];
                    float si = u / (1.f + expf(-u));
                    hrow[wn * 32 + j * 16 + lr] = si * v;
                }
            }
        }
    }
}

__global__ __launch_bounds__(256) void gemm2_mfma(
    const float* __restrict__ hdn, const float* __restrict__ w2,
    const int* __restrict__ cnt, const int* __restrict__ offs,
    const int* __restrict__ idx_list, const float* __restrict__ wgt_list,
    float* __restrict__ out, int e_param, int compact)
{
    int e = (e_param >= 0) ? e_param : (int)blockIdx.z;
    int n_e = cnt[e];
    int row0 = blockIdx.y * 128;
    if (row0 >= n_e) return;
    int col0 = blockIdx.x * 128;
    int lbase = offs[e];
    size_t hbase = compact ? (size_t)lbase : 0;

    __shared__ unsigned short Ah[128 * 32], Al[128 * 32];
    __shared__ unsigned short Bh[128 * 32], Bl[128 * 32];
    __shared__ int   s_tok[128];
    __shared__ float s_wgt[128];

    int tid = threadIdx.x;
    if (tid < 128) {
        int r = row0 + tid;
        s_tok[tid] = (r < n_e) ? idx_list[lbase + r] : -1;
        s_wgt[tid] = (r < n_e) ? wgt_list[lbase + r] : 0.f;
    }

    const float* w2e = w2 + (size_t)e * H_DIM * I_DIM;

    f32x4 acc[4][4];
#pragma unroll
    for (int i = 0; i < 4; i++)
#pragma unroll
        for (int j = 0; j < 4; j++) acc[i][j] = (f32x4)(0.f);

    int lane = tid & 63, wid = tid >> 6;
    int wm = wid >> 1, wn = wid & 1;
    int lr = lane & 15, lq = lane >> 4;

    for (int k0 = 0; k0 < I_DIM; k0 += 32) {
#pragma unroll
        for (int p = 0; p < 4; p++) {
            int idx = tid + p * 256;
            int row = idx >> 3, kq = (idx & 7) << 2;
            float4 v = (row0 + row < n_e)
                ? *(const float4*)&hdn[(hbase + row0 + row) * (size_t)I_DIM + k0 + kq]
                : make_float4(0.f, 0.f, 0.f, 0.f);
            unsigned hi[2], lo[2];
            split4(v, hi, lo);
            int s = SWZ(row, kq);
            *(uint2*)&Ah[s] = make_uint2(hi[0], hi[1]);
            *(uint2*)&Al[s] = make_uint2(lo[0], lo[1]);
        }
#pragma unroll
        for (int p = 0; p < 4; p++) {
            int idx = tid + p * 256;
            int row = idx >> 3, kq = (idx & 7) << 2;
            float4 v = *(const float4*)&w2e[(size_t)(col0 + row) * I_DIM + k0 + kq];
            unsigned hi[2], lo[2];
            split4(v, hi, lo);
            int s = SWZ(row, kq);
            *(uint2*)&Bh[s] = make_uint2(hi[0], hi[1]);
            *(uint2*)&Bl[s] = make_uint2(lo[0], lo[1]);
        }
        __syncthreads();

        bf16x8 ah[4], al[4];
#pragma unroll
        for (int i = 0; i < 4; i++) {
            int r = wm * 64 + i * 16 + lr;
            int s = SWZ(r, lq * 8);
            ah[i] = *(const bf16x8*)&Ah[s];
            al[i] = *(const bf16x8*)&Al[s];
        }
#pragma unroll
        for (int j = 0; j < 4; j++) {
            int rb = wn * 64 + j * 16 + lr;
            int s = SWZ(rb, lq * 8);
            bf16x8 bh = *(const bf16x8*)&Bh[s];
            bf16x8 bl = *(const bf16x8*)&Bl[s];
#pragma unroll
            for (int i = 0; i < 4; i++) {
                acc[i][j] = MFMA16(ah[i], bh, acc[i][j]);
                acc[i][j] = MFMA16(ah[i], bl, acc[i][j]);
                acc[i][j] = MFMA16(al[i], bh, acc[i][j]);
            }
        }
        __syncthreads();
    }

#pragma unroll
    for (int i = 0; i < 4; i++) {
#pragma unroll
        for (int r = 0; r < 4; r++) {
            int lrow = wm * 64 + i * 16 + lq * 4 + r;
            int grow = row0 + lrow;
            if (grow < n_e) {
                int t = s_tok[lrow];
                float wt = s_wgt[lrow];
                float* orow = out + (size_t)t * H_DIM + col0;
#pragma unroll
                for (int j = 0; j < 4; j++)
                    atomicAdd(&orow[wn * 64 + j * 16 + lr], wt * acc[i][j][r]);
            }
        }
    }
}

extern "C" void kernel_launch(void* const* d_in, const int* in_sizes, int n_in,
                              void* d_out, int out_size, void* d_ws, size_t ws_size,
                              hipStream_t stream) {
    const float* x  = (const float*)d_in[0];
    const float* gw = (const float*)d_in[1];
    const float* w1 = (const float*)d_in[2];
    const float* w2 = (const float*)d_in[3];
    const float* w3 = (const float*)d_in[4];
    float* out = (float*)d_out;

    char* ws = (char*)d_ws;
    int*   cnt      = (int*)(ws + 0);
    int*   cursor   = (int*)(ws + 32);
    float* probsum  = (float*)(ws + 64);
    int*   offs     = (int*)(ws + 96);
    int*   tok_e    = (int*)(ws + 256);
    float* tok_w    = (float*)(ws + 256 + 65536);
    int*   idx_list = (int*)(ws + 256 + 2 * 65536);
    float* wgt_list = (float*)(ws + 256 + 3 * 65536);
    size_t buf0     = 256 + 4 * 65536;     // 262400, 256-aligned

    const size_t XP = (size_t)T_TOK * H_DIM * 2;     // x plane: 16.78 MB
    const size_t WP = (size_t)I_DIM * H_DIM * 2;     // weight plane/expert: 4.19 MB
    const size_t DP = (size_t)T_TOK * K_TOP * I_DIM * 2;  // hdn plane: 67.1 MB

    // choose largest expert-group size EG whose layout fits
    int EG = 0;
    size_t xh_o = 0, xl_o = 0, wslot_o = 0, dh_o = 0, dl_o = 0;
    for (int eg = E_EXP; eg >= 1; eg >>= 1) {
        size_t off = buf0;
        size_t a = off; off += XP;           // xh
        size_t b = off; off += XP;           // xl
        size_t c = off; off += 4 * eg * WP;  // wslot (w1h,w1l,w3h,w3l | aliased by w2h,w2l)
        size_t d = off; off += DP;           // hdnh
        size_t f = off; off += DP;           // hdnl
        if (off <= ws_size) { EG = eg; xh_o = a; xl_o = b; wslot_o = c; dh_o = d; dl_o = f; break; }
    }
    size_t need1 = buf0 + (size_t)T_TOK * K_TOP * I_DIM * sizeof(float);

    hipMemsetAsync(ws, 0, 128, stream);
    hipMemsetAsync(d_out, 0, (size_t)T_TOK * H_DIM * sizeof(float), stream);

    gate_kernel<<<T_TOK / 4, 256, 0, stream>>>(x, gw, cnt, probsum, tok_e, tok_w);
    offs_aux_kernel<<<1, 64, 0, stream>>>(cnt, probsum, offs, cursor,
                                          out + (size_t)T_TOK * H_DIM);
    scatter_kernel<<<T_TOK / 256, 256, 0, stream>>>(tok_e, tok_w, cursor,
                                                    idx_list, wgt_list);

    if (EG >= 1) {
        unsigned short* xh = (unsigned short*)(ws + xh_o);
        unsigned short* xl = (unsigned short*)(ws + xl_o);
        unsigned short* dh = (unsigned short*)(ws + dh_o);
        unsigned short* dl = (unsigned short*)(ws + dl_o);
        unsigned short* s_w1h = (unsigned short*)(ws + wslot_o + 0 * EG * WP);
        unsigned short* s_w1l = (unsigned short*)(ws + wslot_o + 1 * EG * WP);
        unsigned short* s_w3h = (unsigned short*)(ws + wslot_o + 2 * EG * WP);
        unsigned short* s_w3l = (unsigned short*)(ws + wslot_o + 3 * EG * WP);
        unsigned short* s_w2h = (unsigned short*)(ws + wslot_o + 0 * EG * WP);
        unsigned short* s_w2l = (unsigned short*)(ws + wslot_o + 1 * EG * WP);

        {   // pre-split x once
            int nch = T_TOK * H_DIM / 8;
            int g = (nch + 255) / 256; if (g > 2048) g = 2048;
            convert_split_kernel<<<g, 256, 0, stream>>>(
                (const float4*)x, (uint4*)xh, (uint4*)xl, nch);
        }
        const int wch = (int)((size_t)EG * I_DIM * H_DIM / 8);
        int wg = (wch + 255) / 256; if (wg > 2048) wg = 2048;

        for (int eb = 0; eb < E_EXP; eb += EG) {
            const size_t woff = (size_t)eb * I_DIM * H_DIM;
            convert_split_kernel<<<wg, 256, 0, stream>>>(
                (const float4*)(w1 + woff), (uint4*)s_w1h, (uint4*)s_w1l, wch);
            convert_split_kernel<<<wg, 256, 0, stream>>>(
                (const float4*)(w3 + woff), (uint4*)s_w3h, (uint4*)s_w3l, wch);
            dim3 g1(I_DIM / 64, T_TOK / 128, EG);
            gemm1_ps<<<g1, 256, 0, stream>>>(xh, xl, s_w1h, s_w1l, s_w3h, s_w3l,
                                             cnt, offs, idx_list, dh, dl, eb);
            convert_split_kernel<<<wg, 256, 0, stream>>>(
                (const float4*)(w2 + woff), (uint4*)s_w2h, (uint4*)s_w2l, wch);
            dim3 g2(H_DIM / 128, T_TOK / 128, EG);
            gemm2_ps<<<g2, 256, 0, stream>>>(dh, dl, s_w2h, s_w2l,
                                             cnt, offs, idx_list, wgt_list, out, eb);
        }
    } else if (ws_size >= need1) {
        float* hdn = (float*)(ws + buf0);
        dim3 g1(I_DIM / 64, T_TOK / 128, E_EXP);
        gemm1_mfma<<<g1, 256, 0, stream>>>(x, w1, w3, cnt, offs, idx_list, hdn, -1, 1);
        dim3 g2(H_DIM / 128, T_TOK / 128, E_EXP);
        gemm2_mfma<<<g2, 256, 0, stream>>>(hdn, w2, cnt, offs, idx_list, wgt_list,
                                           out, -1, 1);
    } else {
        float* hdn = (float*)(ws + buf0);
        for (int e = 0; e < E_EXP; e++) {
            gemm1_mfma<<<dim3(I_DIM / 64, T_TOK / 128, 1), 256, 0, stream>>>(
                x, w1, w3, cnt, offs, idx_list, hdn, e, 0);
            gemm2_mfma<<<dim3(H_DIM / 128, T_TOK / 128, 1), 256, 0, stream>>>(
                hdn, w2, cnt, offs, idx_list, wgt_list, out, e, 0);
        }
    }
}